// Round 9
// baseline (1020.575 us; speedup 1.0000x reference)
//
#include <hip/hip_runtime.h>
#include <hip/hip_bf16.h>
#include <cstdint>

#define DEV __device__ __forceinline__

typedef __bf16 bf16x8 __attribute__((ext_vector_type(8)));
typedef float f32x4 __attribute__((ext_vector_type(4)));
typedef unsigned short ushort_t;
typedef ushort_t ushort8 __attribute__((ext_vector_type(8)));
typedef uint32_t uint2_t __attribute__((ext_vector_type(2)));

DEV ushort_t f2bf(float f) {
  union { float f; uint32_t u; } x; x.f = f;
  uint32_t r = (x.u + 0x7fffu + ((x.u >> 16) & 1u)) >> 16;
  return (ushort_t)r;
}
DEV float bf2f(ushort_t b) {
  union { uint32_t u; float f; } x; x.u = ((uint32_t)b) << 16;
  return x.f;
}
DEV float gelu_exact(float v) {
  return 0.5f * v * (1.0f + erff(v * 0.70710678118654752f));
}
DEV void gload_lds16(const void* g, void* l) {
  __builtin_amdgcn_global_load_lds(
      (const __attribute__((address_space(1))) void*)g,
      (__attribute__((address_space(3))) void*)l, 16, 0, 0);
}
// pack 4 floats -> 4 fp8 e4m3 bytes (OCP, RNE+sat via v_cvt_pk_fp8_f32)
DEV uint32_t pk_fp8x4(float a, float b, float c, float d) {
  int v = __builtin_amdgcn_cvt_pk_fp8_f32(a, b, 0, false);
  v = __builtin_amdgcn_cvt_pk_fp8_f32(c, d, v, true);
  return (uint32_t)v;
}
DEV uint8_t f2fp8(float a) {
  return (uint8_t)(__builtin_amdgcn_cvt_pk_fp8_f32(a, 0.f, 0, false) & 0xff);
}

// ---------------- prep kernels ----------------

__global__ __launch_bounds__(64) void prep_scal(
    const float* __restrict__ conf, const float* __restrict__ age,
    const float* __restrict__ ev, float* __restrict__ base, float* __restrict__ cs) {
  int l = threadIdx.x;  // 64
  float e = ev[l];
  float m = e;
  #pragma unroll
  for (int d = 1; d < 64; d <<= 1) m = fmaxf(m, __shfl_xor(m, d));
  float freq = logf(e + 1.f) / (logf(m + 2.f) + 1e-8f);
  base[l] = 0.2f * expf(-age[l] * (1.f / 200.f)) + 0.15f * freq + 0.1f * conf[l] + 0.09f;
  cs[l] = 0.45f * conf[l];
}

__global__ __launch_bounds__(256) void prep_pnorm(
    const float* __restrict__ protos, const float* __restrict__ b_in,
    float* __restrict__ p_norm, float* __restrict__ dvec) {
  const int s = blockIdx.x, t = threadIdx.x;
  const float* p = protos + (size_t)s * 2048;
  float vals[8];
  float ss = 0.f, sb = 0.f;
  #pragma unroll
  for (int ii = 0; ii < 2; ++ii) {
    float4 v = *(const float4*)(p + t * 8 + ii * 4);
    float4 bi = *(const float4*)(b_in + t * 8 + ii * 4);
    vals[ii * 4 + 0] = v.x; vals[ii * 4 + 1] = v.y; vals[ii * 4 + 2] = v.z; vals[ii * 4 + 3] = v.w;
    ss += v.x * v.x + v.y * v.y + v.z * v.z + v.w * v.w;
    sb += v.x * bi.x + v.y * bi.y + v.z * bi.z + v.w * bi.w;
  }
  #pragma unroll
  for (int d = 1; d < 64; d <<= 1) { ss += __shfl_xor(ss, d); sb += __shfl_xor(sb, d); }
  __shared__ float red[8];
  if ((t & 63) == 0) { red[t >> 6] = ss; red[4 + (t >> 6)] = sb; }
  __syncthreads();
  ss = red[0] + red[1] + red[2] + red[3];
  sb = red[4] + red[5] + red[6] + red[7];
  float inv = 1.f / fmaxf(sqrtf(ss), 1e-12f);
  #pragma unroll
  for (int k = 0; k < 8; ++k) p_norm[(size_t)s * 2048 + t * 8 + k] = vals[k] * inv;
  if (t == 0) dvec[s] = sb * inv;
}

// ---------------- conversion kernels ----------------
// conv_x: writes xa (bf16, lda 2112, for OUT GEMM) AND xa8 (fp8, lda 2048, for HEAD GEMM)
__global__ __launch_bounds__(256) void conv_x(const float* __restrict__ x,
                                              ushort_t* __restrict__ xa,
                                              uint8_t* __restrict__ xa8) {
  size_t e = ((size_t)blockIdx.x * 256 + threadIdx.x) * 8;
  int row = (int)(e >> 11), col = (int)(e & 2047);
  float4 f0 = *(const float4*)(x + e);
  float4 f1 = *(const float4*)(x + e + 4);
  ushort8 o;
  o[0] = f2bf(f0.x); o[1] = f2bf(f0.y); o[2] = f2bf(f0.z); o[3] = f2bf(f0.w);
  o[4] = f2bf(f1.x); o[5] = f2bf(f1.y); o[6] = f2bf(f1.z); o[7] = f2bf(f1.w);
  *(ushort8*)(xa + (size_t)row * 2112 + col) = o;
  uint2_t p;
  p[0] = pk_fp8x4(f0.x, f0.y, f0.z, f0.w);
  p[1] = pk_fp8x4(f1.x, f1.y, f1.z, f1.w);
  *(uint2_t*)(xa8 + (size_t)row * 2048 + col) = p;
}

// fp8 weight matrix for HEAD GEMM: rows 0-2047 W_in, 2048-3071 Wr1, 3072-3135 P2 (small_p2),
// 3136-3199 zeros.
__global__ __launch_bounds__(256) void conv_wbig8(const float* __restrict__ W_in,
                                                  const float* __restrict__ Wr1,
                                                  uint8_t* __restrict__ wbig8) {
  const int row = blockIdx.x;
  const int col = threadIdx.x * 8;
  if (row >= 3072 && row < 3136) return;  // P2 region
  uint2_t p;
  if (row < 3072) {
    const float* src = (row < 2048) ? (W_in + (size_t)row * 2048 + col)
                                    : (Wr1 + (size_t)(row - 2048) * 2048 + col);
    float4 f0 = *(const float4*)(src);
    float4 f1 = *(const float4*)(src + 4);
    p[0] = pk_fp8x4(f0.x, f0.y, f0.z, f0.w);
    p[1] = pk_fp8x4(f1.x, f1.y, f1.z, f1.w);
  } else {
    p[0] = 0u; p[1] = 0u;
  }
  *(uint2_t*)(wbig8 + (size_t)row * 2048 + col) = p;
}

__global__ __launch_bounds__(256) void conv_ww(const float* __restrict__ W_out,
                                               ushort_t* __restrict__ wwm) {
  size_t e = ((size_t)blockIdx.x * 256 + threadIdx.x) * 8;
  int n = (int)(e >> 11), c = (int)(e & 2047);
  float4 f0 = *(const float4*)(W_out + (size_t)n * 4096 + c);
  float4 f1 = *(const float4*)(W_out + (size_t)n * 4096 + c + 4);
  ushort8 o;
  o[0] = f2bf(f0.x); o[1] = f2bf(f0.y); o[2] = f2bf(f0.z); o[3] = f2bf(f0.w);
  o[4] = f2bf(f1.x); o[5] = f2bf(f1.y); o[6] = f2bf(f1.z); o[7] = f2bf(f1.w);
  *(ushort8*)(wwm + (size_t)n * 2112 + c) = o;
}

// P2[s][k] = sum_j p_norm[s][j] * W_in[j][k]  -> fp8 into wbig8 rows 3072+s
__global__ __launch_bounds__(256) void small_p2(const float* __restrict__ p_norm,
                                                const float* __restrict__ W_in,
                                                uint8_t* __restrict__ wbig8) {
  __shared__ float pn[8][128];
  const int t = threadIdx.x;
  const int k = blockIdx.x * 128 + (t & 127);
  const int sh = t >> 7;  // 0/1
  const int s0 = blockIdx.y * 8;
  float acc[4] = {0.f, 0.f, 0.f, 0.f};
  for (int j0 = 0; j0 < 2048; j0 += 128) {
    __syncthreads();
    {
      int sl = t >> 5;           // 0..7
      int j4 = (t & 31) * 4;     // 0..124
      *(float4*)&pn[sl][j4] = *(const float4*)&p_norm[(size_t)(s0 + sl) * 2048 + j0 + j4];
    }
    __syncthreads();
    #pragma unroll 8
    for (int jj = 0; jj < 128; ++jj) {
      float wv = W_in[(size_t)(j0 + jj) * 2048 + k];
      #pragma unroll
      for (int i = 0; i < 4; ++i) acc[i] += pn[sh * 4 + i][jj] * wv;
    }
  }
  #pragma unroll
  for (int i = 0; i < 4; ++i)
    wbig8[(size_t)(3072 + s0 + sh * 4 + i) * 2048 + k] = f2fp8(acc[i]);
}

// Rt[n][s] = sum_k protos[s][k] * W_out[n][2048+k] -> bf16 into wwm cols 2048+s
__global__ __launch_bounds__(256) void small_R(const float* __restrict__ protos,
                                               const float* __restrict__ W_out,
                                               ushort_t* __restrict__ wwm) {
  __shared__ float pch[64][68];
  __shared__ float wch[16][68];
  const int t = threadIdx.x;
  const int n_loc = t >> 4;  // 0..15
  const int sb = t & 15;
  const int n0 = blockIdx.x * 16;
  float acc[4] = {0.f, 0.f, 0.f, 0.f};
  for (int k0 = 0; k0 < 2048; k0 += 64) {
    __syncthreads();
    #pragma unroll
    for (int ii = 0; ii < 4; ++ii) {
      int lin4 = t * 4 + ii;      // 0..1023
      int s = lin4 >> 4;          // 0..63
      int k4 = (lin4 & 15) * 4;
      *(float4*)&pch[s][k4] = *(const float4*)&protos[(size_t)s * 2048 + k0 + k4];
    }
    {
      int n_l = t >> 4;
      int k4 = (t & 15) * 4;
      *(float4*)&wch[n_l][k4] = *(const float4*)&W_out[(size_t)(n0 + n_l) * 4096 + 2048 + k0 + k4];
    }
    __syncthreads();
    #pragma unroll 8
    for (int kk = 0; kk < 64; ++kk) {
      float wv = wch[n_loc][kk];
      #pragma unroll
      for (int i = 0; i < 4; ++i) acc[i] += pch[sb + 16 * i][kk] * wv;
    }
  }
  #pragma unroll
  for (int i = 0; i < 4; ++i)
    wwm[(size_t)(n0 + n_loc) * 2112 + 2048 + sb + 16 * i] = f2bf(acc[i]);
}

// ---------------- HEAD GEMM in fp8 (m97 structure, BK=32) ----------------
// Same schedule as the best-measured R1 bf16 kernel; dtype fp8 e4m3 halves every byte
// stream (global->LDS staging, L2/L3 re-reads, LDS reads). Non-scaled fp8 MFMA runs at
// bf16 rate, so FLOP time is unchanged -- this isolates the byte-throughput hypothesis.
// A=xa8 (16384x2048), B=wbig8 (3200x2048; rows 3136-3199 zero).
// cols<2048 -> rownorm2(+b_in); 2048..3071 -> gelu(+br1)->r_bf; 3072..3135 -> raw_proj.
__global__ __launch_bounds__(256) void gemm_head_fp8(
    const uint8_t* __restrict__ A8, const uint8_t* __restrict__ B8,
    const float* __restrict__ bias0, const float* __restrict__ bias1,
    float* __restrict__ out0, ushort_t* __restrict__ out1, float* __restrict__ out2) {
  __shared__ __align__(16) uint8_t As[128 * 32];  // 4 KB
  __shared__ __align__(16) uint8_t Bs[128 * 32];  // 4 KB
  const int tid = threadIdx.x;
  const int w = tid >> 6, l = tid & 63;
  const int bm = blockIdx.x * 128;
  const int bn = blockIdx.y * 128;
  const int srow = tid >> 1;          // 0..127
  const int scol = (tid & 1) * 16;    // byte offset within 32B row
  const int wm = (w >> 1) * 64, wn = (w & 1) * 64;
  const int lr = l & 15;
  const int lkb = (l >> 4) * 8;       // byte offset: 8 fp8 = 8 K-elems per lane

  f32x4 acc[4][4];
  #pragma unroll
  for (int i = 0; i < 4; ++i)
    #pragma unroll
    for (int j = 0; j < 4; ++j) acc[i][j] = f32x4{0.f, 0.f, 0.f, 0.f};

  for (int k0 = 0; k0 < 2048; k0 += 32) {
    __syncthreads();
    gload_lds16(A8 + (size_t)(bm + srow) * 2048 + k0 + scol, (char*)As + tid * 16);
    gload_lds16(B8 + (size_t)(bn + srow) * 2048 + k0 + scol, (char*)Bs + tid * 16);
    __syncthreads();
    long af[4], bf_[4];
    #pragma unroll
    for (int i = 0; i < 4; ++i) af[i] = *(const long*)&As[(wm + i * 16 + lr) * 32 + lkb];
    #pragma unroll
    for (int j = 0; j < 4; ++j) bf_[j] = *(const long*)&Bs[(wn + j * 16 + lr) * 32 + lkb];
    #pragma unroll
    for (int i = 0; i < 4; ++i)
      #pragma unroll
      for (int j = 0; j < 4; ++j)
        acc[i][j] = __builtin_amdgcn_mfma_f32_16x16x32_fp8_fp8(af[i], bf_[j], acc[i][j], 0, 0, 0);
  }

  const int lg = l >> 4;
  #pragma unroll
  for (int i = 0; i < 4; ++i) {
    #pragma unroll
    for (int q = 0; q < 4; ++q) {
      const int grow = bm + wm + i * 16 + lg * 4 + q;
      float ss = 0.f;
      #pragma unroll
      for (int j = 0; j < 4; ++j) {
        const int gcol = bn + wn + j * 16 + lr;
        float v = acc[i][j][q];
        if (gcol < 2048) {
          v += bias0[gcol];
          ss += v * v;
        } else if (gcol < 3072) {
          v += bias1[gcol - 2048];
          out1[(size_t)grow * 1024 + (gcol - 2048)] = f2bf(gelu_exact(v));
        } else if (gcol < 3136) {
          out2[(size_t)grow * 64 + (gcol - 3072)] = v;
        }
      }
      if (bn < 2048) {
        ss += __shfl_xor(ss, 1);
        ss += __shfl_xor(ss, 2);
        ss += __shfl_xor(ss, 4);
        ss += __shfl_xor(ss, 8);
        if (lr == 0) atomicAdd(&out0[grow], ss);
      }
    }
  }
}

// ---------------- OUT GEMM (bf16, unchanged R1 structure) ----------------
// A=xa (K=2112), B=wwm (2048x2112). out = gelu(acc+b_out)+x -> d_out.
__global__ __launch_bounds__(256) void gemm_out(
    const ushort_t* __restrict__ A, const ushort_t* __restrict__ Bw,
    const float* __restrict__ bias0, const float* __restrict__ x_res,
    float* __restrict__ out0) {
  __shared__ ushort_t As[128 * 32];
  __shared__ ushort_t Bs[128 * 32];
  const int tid = threadIdx.x;
  const int w = tid >> 6, l = tid & 63;
  const int bm = blockIdx.x * 128;
  const int bn = blockIdx.y * 128;
  const int srow = tid >> 2;
  const int scol = (tid & 3) * 8;
  const int wm = (w >> 1) * 64, wn = (w & 1) * 64;
  const int lr = l & 15, lk = (l >> 4) * 8;

  f32x4 acc[4][4];
  #pragma unroll
  for (int i = 0; i < 4; ++i)
    #pragma unroll
    for (int j = 0; j < 4; ++j) acc[i][j] = f32x4{0.f, 0.f, 0.f, 0.f};

  for (int k0 = 0; k0 < 2112; k0 += 32) {
    __syncthreads();
    #pragma unroll
    for (int r = 0; r < 2; ++r) {
      int row = srow + r * 64;
      gload_lds16(A + (size_t)(bm + row) * 2112 + k0 + scol,
                  (char*)As + (size_t)(r * 256 + tid) * 16);
    }
    #pragma unroll
    for (int r = 0; r < 2; ++r) {
      int row = srow + r * 64;
      gload_lds16(Bw + (size_t)(bn + row) * 2112 + k0 + scol,
                  (char*)Bs + (size_t)(r * 256 + tid) * 16);
    }
    __syncthreads();
    bf16x8 af[4], bf_[4];
    #pragma unroll
    for (int i = 0; i < 4; ++i) af[i] = *(const bf16x8*)&As[(wm + i * 16 + lr) * 32 + lk];
    #pragma unroll
    for (int j = 0; j < 4; ++j) bf_[j] = *(const bf16x8*)&Bs[(wn + j * 16 + lr) * 32 + lk];
    #pragma unroll
    for (int i = 0; i < 4; ++i)
      #pragma unroll
      for (int j = 0; j < 4; ++j)
        acc[i][j] = __builtin_amdgcn_mfma_f32_16x16x32_bf16(af[i], bf_[j], acc[i][j], 0, 0, 0);
  }

  const int lg = l >> 4;
  #pragma unroll
  for (int i = 0; i < 4; ++i)
    #pragma unroll
    for (int j = 0; j < 4; ++j)
      #pragma unroll
      for (int q = 0; q < 4; ++q) {
        const int grow = bm + wm + i * 16 + lg * 4 + q;
        const int gcol = bn + wn + j * 16 + lr;
        float v = acc[i][j][q] + bias0[gcol];
        float g = gelu_exact(v);
        out0[(size_t)grow * 2048 + gcol] = g + x_res[(size_t)grow * 2048 + gcol];
      }
}

// ---------------- attention / salience kernel (1 wave per row) ----------------
__global__ __launch_bounds__(256) void attn_k(
    const ushort_t* __restrict__ r_bf, const float* __restrict__ Wr2,
    const float* __restrict__ br2, const float* __restrict__ rn2,
    const float* __restrict__ rproj, const float* __restrict__ dvec,
    const float* __restrict__ base, const float* __restrict__ cs,
    ushort_t* __restrict__ xa) {
  const int b = blockIdx.x * 4 + (threadIdx.x >> 6);
  const int l = threadIdx.x & 63;
  const ushort_t* rrow = r_bf + (size_t)b * 1024;
  float t0 = 0.f, t1 = 0.f, t2 = 0.f, t3 = 0.f;
  #pragma unroll
  for (int m = 0; m < 16; ++m) {
    int k = l + m * 64;
    float rv = bf2f(rrow[k]);
    t0 += rv * Wr2[k];
    t1 += rv * Wr2[1024 + k];
    t2 += rv * Wr2[2048 + k];
    t3 += rv * Wr2[3072 + k];
  }
  #pragma unroll
  for (int d = 1; d < 64; d <<= 1) {
    t0 += __shfl_xor(t0, d); t1 += __shfl_xor(t1, d);
    t2 += __shfl_xor(t2, d); t3 += __shfl_xor(t3, d);
  }
  t0 += br2[0]; t1 += br2[1]; t2 += br2[2]; t3 += br2[3];
  float mx = fmaxf(fmaxf(t0, t1), fmaxf(t2, t3));
  float e0 = expf(t0 - mx), e1 = expf(t1 - mx), e2 = expf(t2 - mx), e3 = expf(t3 - mx);
  float sinv = 1.f / (e0 + e1 + e2 + e3);
  float tw0 = e0 * sinv, tw1 = e1 * sinv, tw2 = e2 * sinv, tw3 = e3 * sinv;
  const int ty = l >> 4;
  float twv = (ty == 0) ? tw0 : ((ty == 1) ? tw1 : ((ty == 2) ? tw2 : tw3));

  float inv = 1.f / fmaxf(sqrtf(rn2[b]), 1e-12f);
  float rp = rproj[(size_t)b * 64 + l] + dvec[l];
  float sal = cs[l] * twv * (rp * inv) + base[l];
  sal = fminf(fmaxf(sal, 0.f), 1.f);
  float logit = sal * (1.f / 0.07f);
  float lm = logit;
  #pragma unroll
  for (int d = 1; d < 64; d <<= 1) lm = fmaxf(lm, __shfl_xor(lm, d));
  float ex = expf(logit - lm);
  float es = ex;
  #pragma unroll
  for (int d = 1; d < 64; d <<= 1) es += __shfl_xor(es, d);
  float attn = ex / es;
  xa[(size_t)b * 2112 + 2048 + l] = f2bf(attn);
}

// ---------------- LayerNorm (in-place on d_out) ----------------
__global__ __launch_bounds__(256) void ln_k(float* __restrict__ y,
                                            const float* __restrict__ lw,
                                            const float* __restrict__ lb) {
  const int b = blockIdx.x, t = threadIdx.x;
  float* row = y + (size_t)b * 2048;
  float4 v0 = *(const float4*)(row + t * 8);
  float4 v1 = *(const float4*)(row + t * 8 + 4);
  float s = v0.x + v0.y + v0.z + v0.w + v1.x + v1.y + v1.z + v1.w;
  float s2 = v0.x * v0.x + v0.y * v0.y + v0.z * v0.z + v0.w * v0.w +
             v1.x * v1.x + v1.y * v1.y + v1.z * v1.z + v1.w * v1.w;
  #pragma unroll
  for (int d = 1; d < 64; d <<= 1) { s += __shfl_xor(s, d); s2 += __shfl_xor(s2, d); }
  __shared__ float red[8];
  if ((t & 63) == 0) { red[t >> 6] = s; red[4 + (t >> 6)] = s2; }
  __syncthreads();
  float ts = red[0] + red[1] + red[2] + red[3];
  float ts2 = red[4] + red[5] + red[6] + red[7];
  const float mu = ts * (1.f / 2048.f);
  const float inv = 1.f / sqrtf(ts2 * (1.f / 2048.f) - mu * mu + 1e-5f);
  float4 w0 = *(const float4*)(lw + t * 8), w1 = *(const float4*)(lw + t * 8 + 4);
  float4 b0 = *(const float4*)(lb + t * 8), b1 = *(const float4*)(lb + t * 8 + 4);
  float4 o0, o1;
  o0.x = (v0.x - mu) * inv * w0.x + b0.x;
  o0.y = (v0.y - mu) * inv * w0.y + b0.y;
  o0.z = (v0.z - mu) * inv * w0.z + b0.z;
  o0.w = (v0.w - mu) * inv * w0.w + b0.w;
  o1.x = (v1.x - mu) * inv * w1.x + b1.x;
  o1.y = (v1.y - mu) * inv * w1.y + b1.y;
  o1.z = (v1.z - mu) * inv * w1.z + b1.z;
  o1.w = (v1.w - mu) * inv * w1.w + b1.w;
  *(float4*)(row + t * 8) = o0;
  *(float4*)(row + t * 8 + 4) = o1;
}

// ---------------- launch ----------------
extern "C" void kernel_launch(void* const* d_in, const int* in_sizes, int n_in,
                              void* d_out, int out_size, void* d_ws, size_t ws_size,
                              hipStream_t stream) {
  const float* x      = (const float*)d_in[0];
  const float* protos = (const float*)d_in[1];
  const float* conf   = (const float*)d_in[2];
  const float* age    = (const float*)d_in[3];
  const float* ev     = (const float*)d_in[4];
  const float* W_in   = (const float*)d_in[5];
  const float* b_in   = (const float*)d_in[6];
  const float* Wr1    = (const float*)d_in[7];
  const float* br1    = (const float*)d_in[8];
  const float* Wr2    = (const float*)d_in[9];
  const float* br2    = (const float*)d_in[10];
  const float* W_out  = (const float*)d_in[11];
  const float* b_out  = (const float*)d_in[12];
  const float* ln_w   = (const float*)d_in[13];
  const float* ln_b   = (const float*)d_in[14];
  float* out = (float*)d_out;

  char* ws = (char*)d_ws;
  size_t off = 0;
  auto take = [&](size_t bytes) {
    char* p = ws + off;
    off = (off + bytes + 255) & ~(size_t)255;
    return p;
  };
  ushort_t* xa    = (ushort_t*)take((size_t)16384 * 2112 * 2);
  uint8_t*  xa8   = (uint8_t*)take((size_t)16384 * 2048);
  uint8_t*  wbig8 = (uint8_t*)take((size_t)3200 * 2048);
  ushort_t* wwm   = (ushort_t*)take((size_t)2048 * 2112 * 2);
  ushort_t* rbf   = (ushort_t*)take((size_t)16384 * 1024 * 2);
  float*    rproj = (float*)take((size_t)16384 * 64 * 4);
  float*    rn2   = (float*)take((size_t)16384 * 4);
  float*    pnorm = (float*)take((size_t)64 * 2048 * 4);
  float*    base  = (float*)take(256);
  float*    cs    = (float*)take(256);
  float*    dvec  = (float*)take(256);
  (void)in_sizes; (void)n_in; (void)out_size; (void)ws_size;

  hipMemsetAsync(rn2, 0, 16384 * 4, stream);
  prep_scal<<<1, 64, 0, stream>>>(conf, age, ev, base, cs);
  prep_pnorm<<<64, 256, 0, stream>>>(protos, b_in, pnorm, dvec);
  conv_x<<<16384, 256, 0, stream>>>(x, xa, xa8);
  conv_wbig8<<<3200, 256, 0, stream>>>(W_in, Wr1, wbig8);
  conv_ww<<<2048, 256, 0, stream>>>(W_out, wwm);
  small_p2<<<dim3(16, 8), 256, 0, stream>>>(pnorm, W_in, wbig8);
  small_R<<<128, 256, 0, stream>>>(protos, W_out, wwm);
  // HEAD GEMM (fp8): M=16384, N=3200 (rows 3136-3199 zero), K=2048
  gemm_head_fp8<<<dim3(128, 25), 256, 0, stream>>>(xa8, wbig8,
                                                   b_in, br1, rn2, rbf, rproj);
  attn_k<<<4096, 256, 0, stream>>>(rbf, Wr2, br2, rn2, rproj, dvec, base, cs, xa);
  // OUT GEMM (bf16): M=16384, N=2048, K=2112
  gemm_out<<<dim3(128, 16), 256, 0, stream>>>(xa, wwm, b_out, x, out);
  ln_k<<<16384, 256, 0, stream>>>(out, ln_w, ln_b);
}

// Round 10
// 1020.343 us; speedup vs baseline: 1.0002x; 1.0002x over previous
//
#include <hip/hip_runtime.h>
#include <hip/hip_bf16.h>
#include <cstdint>

#define DEV __device__ __forceinline__

typedef __bf16 bf16x8 __attribute__((ext_vector_type(8)));
typedef float f32x4 __attribute__((ext_vector_type(4)));
typedef unsigned short ushort_t;
typedef ushort_t ushort8 __attribute__((ext_vector_type(8)));
typedef uint32_t uint2_t __attribute__((ext_vector_type(2)));

DEV ushort_t f2bf(float f) {
  union { float f; uint32_t u; } x; x.f = f;
  uint32_t r = (x.u + 0x7fffu + ((x.u >> 16) & 1u)) >> 16;
  return (ushort_t)r;
}
DEV float bf2f(ushort_t b) {
  union { uint32_t u; float f; } x; x.u = ((uint32_t)b) << 16;
  return x.f;
}
DEV float gelu_exact(float v) {
  return 0.5f * v * (1.0f + erff(v * 0.70710678118654752f));
}
DEV void gload_lds16(const void* g, void* l) {
  __builtin_amdgcn_global_load_lds(
      (const __attribute__((address_space(1))) void*)g,
      (__attribute__((address_space(3))) void*)l, 16, 0, 0);
}
// pack 4 floats -> 4 fp8 e4m3 bytes (OCP, RNE+sat via v_cvt_pk_fp8_f32)
DEV uint32_t pk_fp8x4(float a, float b, float c, float d) {
  int v = __builtin_amdgcn_cvt_pk_fp8_f32(a, b, 0, false);
  v = __builtin_amdgcn_cvt_pk_fp8_f32(c, d, v, true);
  return (uint32_t)v;
}
DEV uint8_t f2fp8(float a) {
  return (uint8_t)(__builtin_amdgcn_cvt_pk_fp8_f32(a, 0.f, 0, false) & 0xff);
}

// ---------------- prep kernels ----------------

__global__ __launch_bounds__(64) void prep_scal(
    const float* __restrict__ conf, const float* __restrict__ age,
    const float* __restrict__ ev, float* __restrict__ base, float* __restrict__ cs) {
  int l = threadIdx.x;  // 64
  float e = ev[l];
  float m = e;
  #pragma unroll
  for (int d = 1; d < 64; d <<= 1) m = fmaxf(m, __shfl_xor(m, d));
  float freq = logf(e + 1.f) / (logf(m + 2.f) + 1e-8f);
  base[l] = 0.2f * expf(-age[l] * (1.f / 200.f)) + 0.15f * freq + 0.1f * conf[l] + 0.09f;
  cs[l] = 0.45f * conf[l];
}

__global__ __launch_bounds__(256) void prep_pnorm(
    const float* __restrict__ protos, const float* __restrict__ b_in,
    float* __restrict__ p_norm, float* __restrict__ dvec) {
  const int s = blockIdx.x, t = threadIdx.x;
  const float* p = protos + (size_t)s * 2048;
  float vals[8];
  float ss = 0.f, sb = 0.f;
  #pragma unroll
  for (int ii = 0; ii < 2; ++ii) {
    float4 v = *(const float4*)(p + t * 8 + ii * 4);
    float4 bi = *(const float4*)(b_in + t * 8 + ii * 4);
    vals[ii * 4 + 0] = v.x; vals[ii * 4 + 1] = v.y; vals[ii * 4 + 2] = v.z; vals[ii * 4 + 3] = v.w;
    ss += v.x * v.x + v.y * v.y + v.z * v.z + v.w * v.w;
    sb += v.x * bi.x + v.y * bi.y + v.z * bi.z + v.w * bi.w;
  }
  #pragma unroll
  for (int d = 1; d < 64; d <<= 1) { ss += __shfl_xor(ss, d); sb += __shfl_xor(sb, d); }
  __shared__ float red[8];
  if ((t & 63) == 0) { red[t >> 6] = ss; red[4 + (t >> 6)] = sb; }
  __syncthreads();
  ss = red[0] + red[1] + red[2] + red[3];
  sb = red[4] + red[5] + red[6] + red[7];
  float inv = 1.f / fmaxf(sqrtf(ss), 1e-12f);
  #pragma unroll
  for (int k = 0; k < 8; ++k) p_norm[(size_t)s * 2048 + t * 8 + k] = vals[k] * inv;
  if (t == 0) dvec[s] = sb * inv;
}

// ---------------- conversion kernels ----------------
// conv_x: writes xa (bf16, lda 2112, for OUT GEMM) AND xa8 (fp8, lda 2048, for HEAD GEMM)
__global__ __launch_bounds__(256) void conv_x(const float* __restrict__ x,
                                              ushort_t* __restrict__ xa,
                                              uint8_t* __restrict__ xa8) {
  size_t e = ((size_t)blockIdx.x * 256 + threadIdx.x) * 8;
  int row = (int)(e >> 11), col = (int)(e & 2047);
  float4 f0 = *(const float4*)(x + e);
  float4 f1 = *(const float4*)(x + e + 4);
  ushort8 o;
  o[0] = f2bf(f0.x); o[1] = f2bf(f0.y); o[2] = f2bf(f0.z); o[3] = f2bf(f0.w);
  o[4] = f2bf(f1.x); o[5] = f2bf(f1.y); o[6] = f2bf(f1.z); o[7] = f2bf(f1.w);
  *(ushort8*)(xa + (size_t)row * 2112 + col) = o;
  uint2_t p;
  p[0] = pk_fp8x4(f0.x, f0.y, f0.z, f0.w);
  p[1] = pk_fp8x4(f1.x, f1.y, f1.z, f1.w);
  *(uint2_t*)(xa8 + (size_t)row * 2048 + col) = p;
}

// fp8 weight matrix for HEAD GEMM: rows 0-2047 W_in, 2048-3071 Wr1, 3072-3135 P2 (small_p2),
// 3136-3199 zeros.
__global__ __launch_bounds__(256) void conv_wbig8(const float* __restrict__ W_in,
                                                  const float* __restrict__ Wr1,
                                                  uint8_t* __restrict__ wbig8) {
  const int row = blockIdx.x;
  const int col = threadIdx.x * 8;
  if (row >= 3072 && row < 3136) return;  // P2 region
  uint2_t p;
  if (row < 3072) {
    const float* src = (row < 2048) ? (W_in + (size_t)row * 2048 + col)
                                    : (Wr1 + (size_t)(row - 2048) * 2048 + col);
    float4 f0 = *(const float4*)(src);
    float4 f1 = *(const float4*)(src + 4);
    p[0] = pk_fp8x4(f0.x, f0.y, f0.z, f0.w);
    p[1] = pk_fp8x4(f1.x, f1.y, f1.z, f1.w);
  } else {
    p[0] = 0u; p[1] = 0u;
  }
  *(uint2_t*)(wbig8 + (size_t)row * 2048 + col) = p;
}

__global__ __launch_bounds__(256) void conv_ww(const float* __restrict__ W_out,
                                               ushort_t* __restrict__ wwm) {
  size_t e = ((size_t)blockIdx.x * 256 + threadIdx.x) * 8;
  int n = (int)(e >> 11), c = (int)(e & 2047);
  float4 f0 = *(const float4*)(W_out + (size_t)n * 4096 + c);
  float4 f1 = *(const float4*)(W_out + (size_t)n * 4096 + c + 4);
  ushort8 o;
  o[0] = f2bf(f0.x); o[1] = f2bf(f0.y); o[2] = f2bf(f0.z); o[3] = f2bf(f0.w);
  o[4] = f2bf(f1.x); o[5] = f2bf(f1.y); o[6] = f2bf(f1.z); o[7] = f2bf(f1.w);
  *(ushort8*)(wwm + (size_t)n * 2112 + c) = o;
}

// P2[s][k] = sum_j p_norm[s][j] * W_in[j][k]  -> fp8 into wbig8 rows 3072+s
__global__ __launch_bounds__(256) void small_p2(const float* __restrict__ p_norm,
                                                const float* __restrict__ W_in,
                                                uint8_t* __restrict__ wbig8) {
  __shared__ float pn[8][128];
  const int t = threadIdx.x;
  const int k = blockIdx.x * 128 + (t & 127);
  const int sh = t >> 7;  // 0/1
  const int s0 = blockIdx.y * 8;
  float acc[4] = {0.f, 0.f, 0.f, 0.f};
  for (int j0 = 0; j0 < 2048; j0 += 128) {
    __syncthreads();
    {
      int sl = t >> 5;           // 0..7
      int j4 = (t & 31) * 4;     // 0..124
      *(float4*)&pn[sl][j4] = *(const float4*)&p_norm[(size_t)(s0 + sl) * 2048 + j0 + j4];
    }
    __syncthreads();
    #pragma unroll 8
    for (int jj = 0; jj < 128; ++jj) {
      float wv = W_in[(size_t)(j0 + jj) * 2048 + k];
      #pragma unroll
      for (int i = 0; i < 4; ++i) acc[i] += pn[sh * 4 + i][jj] * wv;
    }
  }
  #pragma unroll
  for (int i = 0; i < 4; ++i)
    wbig8[(size_t)(3072 + s0 + sh * 4 + i) * 2048 + k] = f2fp8(acc[i]);
}

// Rt[n][s] = sum_k protos[s][k] * W_out[n][2048+k] -> bf16 into wwm cols 2048+s
__global__ __launch_bounds__(256) void small_R(const float* __restrict__ protos,
                                               const float* __restrict__ W_out,
                                               ushort_t* __restrict__ wwm) {
  __shared__ float pch[64][68];
  __shared__ float wch[16][68];
  const int t = threadIdx.x;
  const int n_loc = t >> 4;  // 0..15
  const int sb = t & 15;
  const int n0 = blockIdx.x * 16;
  float acc[4] = {0.f, 0.f, 0.f, 0.f};
  for (int k0 = 0; k0 < 2048; k0 += 64) {
    __syncthreads();
    #pragma unroll
    for (int ii = 0; ii < 4; ++ii) {
      int lin4 = t * 4 + ii;      // 0..1023
      int s = lin4 >> 4;          // 0..63
      int k4 = (lin4 & 15) * 4;
      *(float4*)&pch[s][k4] = *(const float4*)&protos[(size_t)s * 2048 + k0 + k4];
    }
    {
      int n_l = t >> 4;
      int k4 = (t & 15) * 4;
      *(float4*)&wch[n_l][k4] = *(const float4*)&W_out[(size_t)(n0 + n_l) * 4096 + 2048 + k0 + k4];
    }
    __syncthreads();
    #pragma unroll 8
    for (int kk = 0; kk < 64; ++kk) {
      float wv = wch[n_loc][kk];
      #pragma unroll
      for (int i = 0; i < 4; ++i) acc[i] += pch[sb + 16 * i][kk] * wv;
    }
  }
  #pragma unroll
  for (int i = 0; i < 4; ++i)
    wwm[(size_t)(n0 + n_loc) * 2112 + 2048 + sb + 16 * i] = f2bf(acc[i]);
}

// ---------------- HEAD GEMM in fp8 (m97 structure, BK=32) ----------------
// Same schedule as the best-measured R1 bf16 kernel; dtype fp8 e4m3 halves every byte
// stream (global->LDS staging, L2/L3 re-reads, LDS reads). Non-scaled fp8 MFMA runs at
// bf16 rate, so FLOP time is unchanged -- this isolates the byte-throughput hypothesis.
// A=xa8 (16384x2048), B=wbig8 (3200x2048; rows 3136-3199 zero).
// cols<2048 -> rownorm2(+b_in); 2048..3071 -> gelu(+br1)->r_bf; 3072..3135 -> raw_proj.
__global__ __launch_bounds__(256) void gemm_head_fp8(
    const uint8_t* __restrict__ A8, const uint8_t* __restrict__ B8,
    const float* __restrict__ bias0, const float* __restrict__ bias1,
    float* __restrict__ out0, ushort_t* __restrict__ out1, float* __restrict__ out2) {
  __shared__ __align__(16) uint8_t As[128 * 32];  // 4 KB
  __shared__ __align__(16) uint8_t Bs[128 * 32];  // 4 KB
  const int tid = threadIdx.x;
  const int w = tid >> 6, l = tid & 63;
  const int bm = blockIdx.x * 128;
  const int bn = blockIdx.y * 128;
  const int srow = tid >> 1;          // 0..127
  const int scol = (tid & 1) * 16;    // byte offset within 32B row
  const int wm = (w >> 1) * 64, wn = (w & 1) * 64;
  const int lr = l & 15;
  const int lkb = (l >> 4) * 8;       // byte offset: 8 fp8 = 8 K-elems per lane

  f32x4 acc[4][4];
  #pragma unroll
  for (int i = 0; i < 4; ++i)
    #pragma unroll
    for (int j = 0; j < 4; ++j) acc[i][j] = f32x4{0.f, 0.f, 0.f, 0.f};

  for (int k0 = 0; k0 < 2048; k0 += 32) {
    __syncthreads();
    gload_lds16(A8 + (size_t)(bm + srow) * 2048 + k0 + scol, (char*)As + tid * 16);
    gload_lds16(B8 + (size_t)(bn + srow) * 2048 + k0 + scol, (char*)Bs + tid * 16);
    __syncthreads();
    long af[4], bf_[4];
    #pragma unroll
    for (int i = 0; i < 4; ++i) af[i] = *(const long*)&As[(wm + i * 16 + lr) * 32 + lkb];
    #pragma unroll
    for (int j = 0; j < 4; ++j) bf_[j] = *(const long*)&Bs[(wn + j * 16 + lr) * 32 + lkb];
    #pragma unroll
    for (int i = 0; i < 4; ++i)
      #pragma unroll
      for (int j = 0; j < 4; ++j)
        acc[i][j] = __builtin_amdgcn_mfma_f32_16x16x32_fp8_fp8(af[i], bf_[j], acc[i][j], 0, 0, 0);
  }

  const int lg = l >> 4;
  #pragma unroll
  for (int i = 0; i < 4; ++i) {
    #pragma unroll
    for (int q = 0; q < 4; ++q) {
      const int grow = bm + wm + i * 16 + lg * 4 + q;
      float ss = 0.f;
      #pragma unroll
      for (int j = 0; j < 4; ++j) {
        const int gcol = bn + wn + j * 16 + lr;
        float v = acc[i][j][q];
        if (gcol < 2048) {
          v += bias0[gcol];
          ss += v * v;
        } else if (gcol < 3072) {
          v += bias1[gcol - 2048];
          out1[(size_t)grow * 1024 + (gcol - 2048)] = f2bf(gelu_exact(v));
        } else if (gcol < 3136) {
          out2[(size_t)grow * 64 + (gcol - 3072)] = v;
        }
      }
      if (bn < 2048) {
        ss += __shfl_xor(ss, 1);
        ss += __shfl_xor(ss, 2);
        ss += __shfl_xor(ss, 4);
        ss += __shfl_xor(ss, 8);
        if (lr == 0) atomicAdd(&out0[grow], ss);
      }
    }
  }
}

// ---------------- OUT GEMM (bf16, unchanged R1 structure) ----------------
// A=xa (K=2112), B=wwm (2048x2112). out = gelu(acc+b_out)+x -> d_out.
__global__ __launch_bounds__(256) void gemm_out(
    const ushort_t* __restrict__ A, const ushort_t* __restrict__ Bw,
    const float* __restrict__ bias0, const float* __restrict__ x_res,
    float* __restrict__ out0) {
  __shared__ ushort_t As[128 * 32];
  __shared__ ushort_t Bs[128 * 32];
  const int tid = threadIdx.x;
  const int w = tid >> 6, l = tid & 63;
  const int bm = blockIdx.x * 128;
  const int bn = blockIdx.y * 128;
  const int srow = tid >> 2;
  const int scol = (tid & 3) * 8;
  const int wm = (w >> 1) * 64, wn = (w & 1) * 64;
  const int lr = l & 15, lk = (l >> 4) * 8;

  f32x4 acc[4][4];
  #pragma unroll
  for (int i = 0; i < 4; ++i)
    #pragma unroll
    for (int j = 0; j < 4; ++j) acc[i][j] = f32x4{0.f, 0.f, 0.f, 0.f};

  for (int k0 = 0; k0 < 2112; k0 += 32) {
    __syncthreads();
    #pragma unroll
    for (int r = 0; r < 2; ++r) {
      int row = srow + r * 64;
      gload_lds16(A + (size_t)(bm + row) * 2112 + k0 + scol,
                  (char*)As + (size_t)(r * 256 + tid) * 16);
    }
    #pragma unroll
    for (int r = 0; r < 2; ++r) {
      int row = srow + r * 64;
      gload_lds16(Bw + (size_t)(bn + row) * 2112 + k0 + scol,
                  (char*)Bs + (size_t)(r * 256 + tid) * 16);
    }
    __syncthreads();
    bf16x8 af[4], bf_[4];
    #pragma unroll
    for (int i = 0; i < 4; ++i) af[i] = *(const bf16x8*)&As[(wm + i * 16 + lr) * 32 + lk];
    #pragma unroll
    for (int j = 0; j < 4; ++j) bf_[j] = *(const bf16x8*)&Bs[(wn + j * 16 + lr) * 32 + lk];
    #pragma unroll
    for (int i = 0; i < 4; ++i)
      #pragma unroll
      for (int j = 0; j < 4; ++j)
        acc[i][j] = __builtin_amdgcn_mfma_f32_16x16x32_bf16(af[i], bf_[j], acc[i][j], 0, 0, 0);
  }

  const int lg = l >> 4;
  #pragma unroll
  for (int i = 0; i < 4; ++i)
    #pragma unroll
    for (int j = 0; j < 4; ++j)
      #pragma unroll
      for (int q = 0; q < 4; ++q) {
        const int grow = bm + wm + i * 16 + lg * 4 + q;
        const int gcol = bn + wn + j * 16 + lr;
        float v = acc[i][j][q] + bias0[gcol];
        float g = gelu_exact(v);
        out0[(size_t)grow * 2048 + gcol] = g + x_res[(size_t)grow * 2048 + gcol];
      }
}

// ---------------- attention / salience kernel (1 wave per row) ----------------
__global__ __launch_bounds__(256) void attn_k(
    const ushort_t* __restrict__ r_bf, const float* __restrict__ Wr2,
    const float* __restrict__ br2, const float* __restrict__ rn2,
    const float* __restrict__ rproj, const float* __restrict__ dvec,
    const float* __restrict__ base, const float* __restrict__ cs,
    ushort_t* __restrict__ xa) {
  const int b = blockIdx.x * 4 + (threadIdx.x >> 6);
  const int l = threadIdx.x & 63;
  const ushort_t* rrow = r_bf + (size_t)b * 1024;
  float t0 = 0.f, t1 = 0.f, t2 = 0.f, t3 = 0.f;
  #pragma unroll
  for (int m = 0; m < 16; ++m) {
    int k = l + m * 64;
    float rv = bf2f(rrow[k]);
    t0 += rv * Wr2[k];
    t1 += rv * Wr2[1024 + k];
    t2 += rv * Wr2[2048 + k];
    t3 += rv * Wr2[3072 + k];
  }
  #pragma unroll
  for (int d = 1; d < 64; d <<= 1) {
    t0 += __shfl_xor(t0, d); t1 += __shfl_xor(t1, d);
    t2 += __shfl_xor(t2, d); t3 += __shfl_xor(t3, d);
  }
  t0 += br2[0]; t1 += br2[1]; t2 += br2[2]; t3 += br2[3];
  float mx = fmaxf(fmaxf(t0, t1), fmaxf(t2, t3));
  float e0 = expf(t0 - mx), e1 = expf(t1 - mx), e2 = expf(t2 - mx), e3 = expf(t3 - mx);
  float sinv = 1.f / (e0 + e1 + e2 + e3);
  float tw0 = e0 * sinv, tw1 = e1 * sinv, tw2 = e2 * sinv, tw3 = e3 * sinv;
  const int ty = l >> 4;
  float twv = (ty == 0) ? tw0 : ((ty == 1) ? tw1 : ((ty == 2) ? tw2 : tw3));

  float inv = 1.f / fmaxf(sqrtf(rn2[b]), 1e-12f);
  float rp = rproj[(size_t)b * 64 + l] + dvec[l];
  float sal = cs[l] * twv * (rp * inv) + base[l];
  sal = fminf(fmaxf(sal, 0.f), 1.f);
  float logit = sal * (1.f / 0.07f);
  float lm = logit;
  #pragma unroll
  for (int d = 1; d < 64; d <<= 1) lm = fmaxf(lm, __shfl_xor(lm, d));
  float ex = expf(logit - lm);
  float es = ex;
  #pragma unroll
  for (int d = 1; d < 64; d <<= 1) es += __shfl_xor(es, d);
  float attn = ex / es;
  xa[(size_t)b * 2112 + 2048 + l] = f2bf(attn);
}

// ---------------- LayerNorm (in-place on d_out) ----------------
__global__ __launch_bounds__(256) void ln_k(float* __restrict__ y,
                                            const float* __restrict__ lw,
                                            const float* __restrict__ lb) {
  const int b = blockIdx.x, t = threadIdx.x;
  float* row = y + (size_t)b * 2048;
  float4 v0 = *(const float4*)(row + t * 8);
  float4 v1 = *(const float4*)(row + t * 8 + 4);
  float s = v0.x + v0.y + v0.z + v0.w + v1.x + v1.y + v1.z + v1.w;
  float s2 = v0.x * v0.x + v0.y * v0.y + v0.z * v0.z + v0.w * v0.w +
             v1.x * v1.x + v1.y * v1.y + v1.z * v1.z + v1.w * v1.w;
  #pragma unroll
  for (int d = 1; d < 64; d <<= 1) { s += __shfl_xor(s, d); s2 += __shfl_xor(s2, d); }
  __shared__ float red[8];
  if ((t & 63) == 0) { red[t >> 6] = s; red[4 + (t >> 6)] = s2; }
  __syncthreads();
  float ts = red[0] + red[1] + red[2] + red[3];
  float ts2 = red[4] + red[5] + red[6] + red[7];
  const float mu = ts * (1.f / 2048.f);
  const float inv = 1.f / sqrtf(ts2 * (1.f / 2048.f) - mu * mu + 1e-5f);
  float4 w0 = *(const float4*)(lw + t * 8), w1 = *(const float4*)(lw + t * 8 + 4);
  float4 b0 = *(const float4*)(lb + t * 8), b1 = *(const float4*)(lb + t * 8 + 4);
  float4 o0, o1;
  o0.x = (v0.x - mu) * inv * w0.x + b0.x;
  o0.y = (v0.y - mu) * inv * w0.y + b0.y;
  o0.z = (v0.z - mu) * inv * w0.z + b0.z;
  o0.w = (v0.w - mu) * inv * w0.w + b0.w;
  o1.x = (v1.x - mu) * inv * w1.x + b1.x;
  o1.y = (v1.y - mu) * inv * w1.y + b1.y;
  o1.z = (v1.z - mu) * inv * w1.z + b1.z;
  o1.w = (v1.w - mu) * inv * w1.w + b1.w;
  *(float4*)(row + t * 8) = o0;
  *(float4*)(row + t * 8 + 4) = o1;
}

// ---------------- launch ----------------
extern "C" void kernel_launch(void* const* d_in, const int* in_sizes, int n_in,
                              void* d_out, int out_size, void* d_ws, size_t ws_size,
                              hipStream_t stream) {
  const float* x      = (const float*)d_in[0];
  const float* protos = (const float*)d_in[1];
  const float* conf   = (const float*)d_in[2];
  const float* age    = (const float*)d_in[3];
  const float* ev     = (const float*)d_in[4];
  const float* W_in   = (const float*)d_in[5];
  const float* b_in   = (const float*)d_in[6];
  const float* Wr1    = (const float*)d_in[7];
  const float* br1    = (const float*)d_in[8];
  const float* Wr2    = (const float*)d_in[9];
  const float* br2    = (const float*)d_in[10];
  const float* W_out  = (const float*)d_in[11];
  const float* b_out  = (const float*)d_in[12];
  const float* ln_w   = (const float*)d_in[13];
  const float* ln_b   = (const float*)d_in[14];
  float* out = (float*)d_out;

  char* ws = (char*)d_ws;
  size_t off = 0;
  auto take = [&](size_t bytes) {
    char* p = ws + off;
    off = (off + bytes + 255) & ~(size_t)255;
    return p;
  };
  ushort_t* xa    = (ushort_t*)take((size_t)16384 * 2112 * 2);
  uint8_t*  xa8   = (uint8_t*)take((size_t)16384 * 2048);
  uint8_t*  wbig8 = (uint8_t*)take((size_t)3200 * 2048);
  ushort_t* wwm   = (ushort_t*)take((size_t)2048 * 2112 * 2);
  ushort_t* rbf   = (ushort_t*)take((size_t)16384 * 1024 * 2);
  float*    rproj = (float*)take((size_t)16384 * 64 * 4);
  float*    rn2   = (float*)take((size_t)16384 * 4);
  float*    pnorm = (float*)take((size_t)64 * 2048 * 4);
  float*    base  = (float*)take(256);
  float*    cs    = (float*)take(256);
  float*    dvec  = (float*)take(256);
  (void)in_sizes; (void)n_in; (void)out_size; (void)ws_size;

  hipMemsetAsync(rn2, 0, 16384 * 4, stream);
  prep_scal<<<1, 64, 0, stream>>>(conf, age, ev, base, cs);
  prep_pnorm<<<64, 256, 0, stream>>>(protos, b_in, pnorm, dvec);
  conv_x<<<16384, 256, 0, stream>>>(x, xa, xa8);
  conv_wbig8<<<3200, 256, 0, stream>>>(W_in, Wr1, wbig8);
  conv_ww<<<2048, 256, 0, stream>>>(W_out, wwm);
  small_p2<<<dim3(16, 8), 256, 0, stream>>>(pnorm, W_in, wbig8);
  small_R<<<128, 256, 0, stream>>>(protos, W_out, wwm);
  // HEAD GEMM (fp8): M=16384, N=3200 (rows 3136-3199 zero), K=2048
  gemm_head_fp8<<<dim3(128, 25), 256, 0, stream>>>(xa8, wbig8,
                                                   b_in, br1, rn2, rbf, rproj);
  attn_k<<<4096, 256, 0, stream>>>(rbf, Wr2, br2, rn2, rproj, dvec, base, cs, xa);
  // OUT GEMM (bf16): M=16384, N=2048, K=2112
  gemm_out<<<dim3(128, 16), 256, 0, stream>>>(xa, wwm, b_out, x, out);
  ln_k<<<16384, 256, 0, stream>>>(out, ln_w, ln_b);
}

// Round 11
// 970.225 us; speedup vs baseline: 1.0519x; 1.0517x over previous
//
#include <hip/hip_runtime.h>
#include <hip/hip_bf16.h>
#include <cstdint>

#define DEV __device__ __forceinline__

typedef __bf16 bf16x8 __attribute__((ext_vector_type(8)));
typedef float f32x4 __attribute__((ext_vector_type(4)));
typedef unsigned short ushort_t;
typedef ushort_t ushort8 __attribute__((ext_vector_type(8)));
typedef uint32_t uint2_t __attribute__((ext_vector_type(2)));

DEV ushort_t f2bf(float f) {
  union { float f; uint32_t u; } x; x.f = f;
  uint32_t r = (x.u + 0x7fffu + ((x.u >> 16) & 1u)) >> 16;
  return (ushort_t)r;
}
DEV float bf2f(ushort_t b) {
  union { uint32_t u; float f; } x; x.u = ((uint32_t)b) << 16;
  return x.f;
}
DEV float gelu_exact(float v) {
  return 0.5f * v * (1.0f + erff(v * 0.70710678118654752f));
}
DEV void gload_lds16(const void* g, void* l) {
  __builtin_amdgcn_global_load_lds(
      (const __attribute__((address_space(1))) void*)g,
      (__attribute__((address_space(3))) void*)l, 16, 0, 0);
}
// pack 4 floats -> 4 fp8 e4m3 bytes (OCP, RNE+sat via v_cvt_pk_fp8_f32)
DEV uint32_t pk_fp8x4(float a, float b, float c, float d) {
  int v = __builtin_amdgcn_cvt_pk_fp8_f32(a, b, 0, false);
  v = __builtin_amdgcn_cvt_pk_fp8_f32(c, d, v, true);
  return (uint32_t)v;
}
DEV uint8_t f2fp8(float a) {
  return (uint8_t)(__builtin_amdgcn_cvt_pk_fp8_f32(a, 0.f, 0, false) & 0xff);
}

// ---------------- prep kernels ----------------

__global__ __launch_bounds__(64) void prep_scal(
    const float* __restrict__ conf, const float* __restrict__ age,
    const float* __restrict__ ev, float* __restrict__ base, float* __restrict__ cs) {
  int l = threadIdx.x;  // 64
  float e = ev[l];
  float m = e;
  #pragma unroll
  for (int d = 1; d < 64; d <<= 1) m = fmaxf(m, __shfl_xor(m, d));
  float freq = logf(e + 1.f) / (logf(m + 2.f) + 1e-8f);
  base[l] = 0.2f * expf(-age[l] * (1.f / 200.f)) + 0.15f * freq + 0.1f * conf[l] + 0.09f;
  cs[l] = 0.45f * conf[l];
}

__global__ __launch_bounds__(256) void prep_pnorm(
    const float* __restrict__ protos, const float* __restrict__ b_in,
    float* __restrict__ p_norm, float* __restrict__ dvec) {
  const int s = blockIdx.x, t = threadIdx.x;
  const float* p = protos + (size_t)s * 2048;
  float vals[8];
  float ss = 0.f, sb = 0.f;
  #pragma unroll
  for (int ii = 0; ii < 2; ++ii) {
    float4 v = *(const float4*)(p + t * 8 + ii * 4);
    float4 bi = *(const float4*)(b_in + t * 8 + ii * 4);
    vals[ii * 4 + 0] = v.x; vals[ii * 4 + 1] = v.y; vals[ii * 4 + 2] = v.z; vals[ii * 4 + 3] = v.w;
    ss += v.x * v.x + v.y * v.y + v.z * v.z + v.w * v.w;
    sb += v.x * bi.x + v.y * bi.y + v.z * bi.z + v.w * bi.w;
  }
  #pragma unroll
  for (int d = 1; d < 64; d <<= 1) { ss += __shfl_xor(ss, d); sb += __shfl_xor(sb, d); }
  __shared__ float red[8];
  if ((t & 63) == 0) { red[t >> 6] = ss; red[4 + (t >> 6)] = sb; }
  __syncthreads();
  ss = red[0] + red[1] + red[2] + red[3];
  sb = red[4] + red[5] + red[6] + red[7];
  float inv = 1.f / fmaxf(sqrtf(ss), 1e-12f);
  #pragma unroll
  for (int k = 0; k < 8; ++k) p_norm[(size_t)s * 2048 + t * 8 + k] = vals[k] * inv;
  if (t == 0) dvec[s] = sb * inv;
}

// ---------------- conversion kernels ----------------
// conv_x: writes xa (bf16, lda 2112, for OUT GEMM) AND xa8 (fp8, lda 2048, for HEAD GEMM)
__global__ __launch_bounds__(256) void conv_x(const float* __restrict__ x,
                                              ushort_t* __restrict__ xa,
                                              uint8_t* __restrict__ xa8) {
  size_t e = ((size_t)blockIdx.x * 256 + threadIdx.x) * 8;
  int row = (int)(e >> 11), col = (int)(e & 2047);
  float4 f0 = *(const float4*)(x + e);
  float4 f1 = *(const float4*)(x + e + 4);
  ushort8 o;
  o[0] = f2bf(f0.x); o[1] = f2bf(f0.y); o[2] = f2bf(f0.z); o[3] = f2bf(f0.w);
  o[4] = f2bf(f1.x); o[5] = f2bf(f1.y); o[6] = f2bf(f1.z); o[7] = f2bf(f1.w);
  *(ushort8*)(xa + (size_t)row * 2112 + col) = o;
  uint2_t p;
  p[0] = pk_fp8x4(f0.x, f0.y, f0.z, f0.w);
  p[1] = pk_fp8x4(f1.x, f1.y, f1.z, f1.w);
  *(uint2_t*)(xa8 + (size_t)row * 2048 + col) = p;
}

// fp8 weight matrix for HEAD GEMM: rows 0-2047 W_in, 2048-3071 Wr1, 3072-3135 P2 (small_p2),
// 3136-3199 zeros.
__global__ __launch_bounds__(256) void conv_wbig8(const float* __restrict__ W_in,
                                                  const float* __restrict__ Wr1,
                                                  uint8_t* __restrict__ wbig8) {
  const int row = blockIdx.x;
  const int col = threadIdx.x * 8;
  if (row >= 3072 && row < 3136) return;  // P2 region
  uint2_t p;
  if (row < 3072) {
    const float* src = (row < 2048) ? (W_in + (size_t)row * 2048 + col)
                                    : (Wr1 + (size_t)(row - 2048) * 2048 + col);
    float4 f0 = *(const float4*)(src);
    float4 f1 = *(const float4*)(src + 4);
    p[0] = pk_fp8x4(f0.x, f0.y, f0.z, f0.w);
    p[1] = pk_fp8x4(f1.x, f1.y, f1.z, f1.w);
  } else {
    p[0] = 0u; p[1] = 0u;
  }
  *(uint2_t*)(wbig8 + (size_t)row * 2048 + col) = p;
}

__global__ __launch_bounds__(256) void conv_ww(const float* __restrict__ W_out,
                                               ushort_t* __restrict__ wwm) {
  size_t e = ((size_t)blockIdx.x * 256 + threadIdx.x) * 8;
  int n = (int)(e >> 11), c = (int)(e & 2047);
  float4 f0 = *(const float4*)(W_out + (size_t)n * 4096 + c);
  float4 f1 = *(const float4*)(W_out + (size_t)n * 4096 + c + 4);
  ushort8 o;
  o[0] = f2bf(f0.x); o[1] = f2bf(f0.y); o[2] = f2bf(f0.z); o[3] = f2bf(f0.w);
  o[4] = f2bf(f1.x); o[5] = f2bf(f1.y); o[6] = f2bf(f1.z); o[7] = f2bf(f1.w);
  *(ushort8*)(wwm + (size_t)n * 2112 + c) = o;
}

// P2[s][k] = sum_j p_norm[s][j] * W_in[j][k]  -> fp8 into wbig8 rows 3072+s
__global__ __launch_bounds__(256) void small_p2(const float* __restrict__ p_norm,
                                                const float* __restrict__ W_in,
                                                uint8_t* __restrict__ wbig8) {
  __shared__ float pn[8][128];
  const int t = threadIdx.x;
  const int k = blockIdx.x * 128 + (t & 127);
  const int sh = t >> 7;  // 0/1
  const int s0 = blockIdx.y * 8;
  float acc[4] = {0.f, 0.f, 0.f, 0.f};
  for (int j0 = 0; j0 < 2048; j0 += 128) {
    __syncthreads();
    {
      int sl = t >> 5;           // 0..7
      int j4 = (t & 31) * 4;     // 0..124
      *(float4*)&pn[sl][j4] = *(const float4*)&p_norm[(size_t)(s0 + sl) * 2048 + j0 + j4];
    }
    __syncthreads();
    #pragma unroll 8
    for (int jj = 0; jj < 128; ++jj) {
      float wv = W_in[(size_t)(j0 + jj) * 2048 + k];
      #pragma unroll
      for (int i = 0; i < 4; ++i) acc[i] += pn[sh * 4 + i][jj] * wv;
    }
  }
  #pragma unroll
  for (int i = 0; i < 4; ++i)
    wbig8[(size_t)(3072 + s0 + sh * 4 + i) * 2048 + k] = f2fp8(acc[i]);
}

// Rt[n][s] = sum_k protos[s][k] * W_out[n][2048+k] -> bf16 into wwm cols 2048+s
__global__ __launch_bounds__(256) void small_R(const float* __restrict__ protos,
                                               const float* __restrict__ W_out,
                                               ushort_t* __restrict__ wwm) {
  __shared__ float pch[64][68];
  __shared__ float wch[16][68];
  const int t = threadIdx.x;
  const int n_loc = t >> 4;  // 0..15
  const int sb = t & 15;
  const int n0 = blockIdx.x * 16;
  float acc[4] = {0.f, 0.f, 0.f, 0.f};
  for (int k0 = 0; k0 < 2048; k0 += 64) {
    __syncthreads();
    #pragma unroll
    for (int ii = 0; ii < 4; ++ii) {
      int lin4 = t * 4 + ii;      // 0..1023
      int s = lin4 >> 4;          // 0..63
      int k4 = (lin4 & 15) * 4;
      *(float4*)&pch[s][k4] = *(const float4*)&protos[(size_t)s * 2048 + k0 + k4];
    }
    {
      int n_l = t >> 4;
      int k4 = (t & 15) * 4;
      *(float4*)&wch[n_l][k4] = *(const float4*)&W_out[(size_t)(n0 + n_l) * 4096 + 2048 + k0 + k4];
    }
    __syncthreads();
    #pragma unroll 8
    for (int kk = 0; kk < 64; ++kk) {
      float wv = wch[n_loc][kk];
      #pragma unroll
      for (int i = 0; i < 4; ++i) acc[i] += pch[sb + 16 * i][kk] * wv;
    }
  }
  #pragma unroll
  for (int i = 0; i < 4; ++i)
    wwm[(size_t)(n0 + n_loc) * 2112 + 2048 + sb + 16 * i] = f2bf(acc[i]);
}

// ---------------- HEAD GEMM in fp8 (m97 structure, BK=32, bank-swizzled LDS) --------
// R10 showed fp8 halves FETCH but adds 3x LDS bank conflicts (32B rows: lanes lr,lr+4
// share a bank; 7.9e7 conflict-cycles). Fix: 1-bit chunk swizzle at 16B granularity:
// stage global source chunk ^= (row>>2)&1 (linear LDS dest, rule #21), read with the
// matching XOR. Banks: dword = 8(lr&3) + 4((lg>>1)^((lr>>2)&1)) + 2(lg&1) -> 16 rows
// map to 8 slots x 2-way, and 2-way aliasing is free (m136).
// A=xa8 (16384x2048), B=wbig8 (3200x2048; rows 3136-3199 zero).
// cols<2048 -> rownorm2(+b_in); 2048..3071 -> gelu(+br1)->r_bf; 3072..3135 -> raw_proj.
__global__ __launch_bounds__(256) void gemm_head_fp8(
    const uint8_t* __restrict__ A8, const uint8_t* __restrict__ B8,
    const float* __restrict__ bias0, const float* __restrict__ bias1,
    float* __restrict__ out0, ushort_t* __restrict__ out1, float* __restrict__ out2) {
  __shared__ __align__(16) uint8_t As[128 * 32];  // 4 KB
  __shared__ __align__(16) uint8_t Bs[128 * 32];  // 4 KB
  const int tid = threadIdx.x;
  const int w = tid >> 6, l = tid & 63;
  const int bm = blockIdx.x * 128;
  const int bn = blockIdx.y * 128;
  const int srow = tid >> 1;          // 0..127
  // swizzled global-source 16B chunk: c' = (tid&1) ^ ((srow>>2)&1); LDS dest stays linear
  const int scol = (((tid & 1) ^ ((srow >> 2) & 1)) * 16);
  const int wm = (w >> 1) * 64, wn = (w & 1) * 64;
  const int lr = l & 15;
  const int lg = l >> 4;              // 0..3 : which 8-fp8 K-chunk
  // swizzled read byte offset within the 32B row
  const int ch = (((lg >> 1) ^ ((lr >> 2) & 1)) << 4) + ((lg & 1) * 8);

  f32x4 acc[4][4];
  #pragma unroll
  for (int i = 0; i < 4; ++i)
    #pragma unroll
    for (int j = 0; j < 4; ++j) acc[i][j] = f32x4{0.f, 0.f, 0.f, 0.f};

  for (int k0 = 0; k0 < 2048; k0 += 32) {
    __syncthreads();
    gload_lds16(A8 + (size_t)(bm + srow) * 2048 + k0 + scol, (char*)As + tid * 16);
    gload_lds16(B8 + (size_t)(bn + srow) * 2048 + k0 + scol, (char*)Bs + tid * 16);
    __syncthreads();
    long af[4], bf_[4];
    #pragma unroll
    for (int i = 0; i < 4; ++i) af[i] = *(const long*)&As[(wm + i * 16 + lr) * 32 + ch];
    #pragma unroll
    for (int j = 0; j < 4; ++j) bf_[j] = *(const long*)&Bs[(wn + j * 16 + lr) * 32 + ch];
    #pragma unroll
    for (int i = 0; i < 4; ++i)
      #pragma unroll
      for (int j = 0; j < 4; ++j)
        acc[i][j] = __builtin_amdgcn_mfma_f32_16x16x32_fp8_fp8(af[i], bf_[j], acc[i][j], 0, 0, 0);
  }

  const int lg2 = l >> 4;
  #pragma unroll
  for (int i = 0; i < 4; ++i) {
    #pragma unroll
    for (int q = 0; q < 4; ++q) {
      const int grow = bm + wm + i * 16 + lg2 * 4 + q;
      float ss = 0.f;
      #pragma unroll
      for (int j = 0; j < 4; ++j) {
        const int gcol = bn + wn + j * 16 + lr;
        float v = acc[i][j][q];
        if (gcol < 2048) {
          v += bias0[gcol];
          ss += v * v;
        } else if (gcol < 3072) {
          v += bias1[gcol - 2048];
          out1[(size_t)grow * 1024 + (gcol - 2048)] = f2bf(gelu_exact(v));
        } else if (gcol < 3136) {
          out2[(size_t)grow * 64 + (gcol - 3072)] = v;
        }
      }
      if (bn < 2048) {
        ss += __shfl_xor(ss, 1);
        ss += __shfl_xor(ss, 2);
        ss += __shfl_xor(ss, 4);
        ss += __shfl_xor(ss, 8);
        if (lr == 0) atomicAdd(&out0[grow], ss);
      }
    }
  }
}

// ---------------- OUT GEMM (bf16, unchanged R1 structure) ----------------
// A=xa (K=2112), B=wwm (2048x2112). out = gelu(acc+b_out)+x -> d_out.
__global__ __launch_bounds__(256) void gemm_out(
    const ushort_t* __restrict__ A, const ushort_t* __restrict__ Bw,
    const float* __restrict__ bias0, const float* __restrict__ x_res,
    float* __restrict__ out0) {
  __shared__ ushort_t As[128 * 32];
  __shared__ ushort_t Bs[128 * 32];
  const int tid = threadIdx.x;
  const int w = tid >> 6, l = tid & 63;
  const int bm = blockIdx.x * 128;
  const int bn = blockIdx.y * 128;
  const int srow = tid >> 2;
  const int scol = (tid & 3) * 8;
  const int wm = (w >> 1) * 64, wn = (w & 1) * 64;
  const int lr = l & 15, lk = (l >> 4) * 8;

  f32x4 acc[4][4];
  #pragma unroll
  for (int i = 0; i < 4; ++i)
    #pragma unroll
    for (int j = 0; j < 4; ++j) acc[i][j] = f32x4{0.f, 0.f, 0.f, 0.f};

  for (int k0 = 0; k0 < 2112; k0 += 32) {
    __syncthreads();
    #pragma unroll
    for (int r = 0; r < 2; ++r) {
      int row = srow + r * 64;
      gload_lds16(A + (size_t)(bm + row) * 2112 + k0 + scol,
                  (char*)As + (size_t)(r * 256 + tid) * 16);
    }
    #pragma unroll
    for (int r = 0; r < 2; ++r) {
      int row = srow + r * 64;
      gload_lds16(Bw + (size_t)(bn + row) * 2112 + k0 + scol,
                  (char*)Bs + (size_t)(r * 256 + tid) * 16);
    }
    __syncthreads();
    bf16x8 af[4], bf_[4];
    #pragma unroll
    for (int i = 0; i < 4; ++i) af[i] = *(const bf16x8*)&As[(wm + i * 16 + lr) * 32 + lk];
    #pragma unroll
    for (int j = 0; j < 4; ++j) bf_[j] = *(const bf16x8*)&Bs[(wn + j * 16 + lr) * 32 + lk];
    #pragma unroll
    for (int i = 0; i < 4; ++i)
      #pragma unroll
      for (int j = 0; j < 4; ++j)
        acc[i][j] = __builtin_amdgcn_mfma_f32_16x16x32_bf16(af[i], bf_[j], acc[i][j], 0, 0, 0);
  }

  const int lg = l >> 4;
  #pragma unroll
  for (int i = 0; i < 4; ++i)
    #pragma unroll
    for (int j = 0; j < 4; ++j)
      #pragma unroll
      for (int q = 0; q < 4; ++q) {
        const int grow = bm + wm + i * 16 + lg * 4 + q;
        const int gcol = bn + wn + j * 16 + lr;
        float v = acc[i][j][q] + bias0[gcol];
        float g = gelu_exact(v);
        out0[(size_t)grow * 2048 + gcol] = g + x_res[(size_t)grow * 2048 + gcol];
      }
}

// ---------------- attention / salience kernel (1 wave per row) ----------------
__global__ __launch_bounds__(256) void attn_k(
    const ushort_t* __restrict__ r_bf, const float* __restrict__ Wr2,
    const float* __restrict__ br2, const float* __restrict__ rn2,
    const float* __restrict__ rproj, const float* __restrict__ dvec,
    const float* __restrict__ base, const float* __restrict__ cs,
    ushort_t* __restrict__ xa) {
  const int b = blockIdx.x * 4 + (threadIdx.x >> 6);
  const int l = threadIdx.x & 63;
  const ushort_t* rrow = r_bf + (size_t)b * 1024;
  float t0 = 0.f, t1 = 0.f, t2 = 0.f, t3 = 0.f;
  #pragma unroll
  for (int m = 0; m < 16; ++m) {
    int k = l + m * 64;
    float rv = bf2f(rrow[k]);
    t0 += rv * Wr2[k];
    t1 += rv * Wr2[1024 + k];
    t2 += rv * Wr2[2048 + k];
    t3 += rv * Wr2[3072 + k];
  }
  #pragma unroll
  for (int d = 1; d < 64; d <<= 1) {
    t0 += __shfl_xor(t0, d); t1 += __shfl_xor(t1, d);
    t2 += __shfl_xor(t2, d); t3 += __shfl_xor(t3, d);
  }
  t0 += br2[0]; t1 += br2[1]; t2 += br2[2]; t3 += br2[3];
  float mx = fmaxf(fmaxf(t0, t1), fmaxf(t2, t3));
  float e0 = expf(t0 - mx), e1 = expf(t1 - mx), e2 = expf(t2 - mx), e3 = expf(t3 - mx);
  float sinv = 1.f / (e0 + e1 + e2 + e3);
  float tw0 = e0 * sinv, tw1 = e1 * sinv, tw2 = e2 * sinv, tw3 = e3 * sinv;
  const int ty = l >> 4;
  float twv = (ty == 0) ? tw0 : ((ty == 1) ? tw1 : ((ty == 2) ? tw2 : tw3));

  float inv = 1.f / fmaxf(sqrtf(rn2[b]), 1e-12f);
  float rp = rproj[(size_t)b * 64 + l] + dvec[l];
  float sal = cs[l] * twv * (rp * inv) + base[l];
  sal = fminf(fmaxf(sal, 0.f), 1.f);
  float logit = sal * (1.f / 0.07f);
  float lm = logit;
  #pragma unroll
  for (int d = 1; d < 64; d <<= 1) lm = fmaxf(lm, __shfl_xor(lm, d));
  float ex = expf(logit - lm);
  float es = ex;
  #pragma unroll
  for (int d = 1; d < 64; d <<= 1) es += __shfl_xor(es, d);
  float attn = ex / es;
  xa[(size_t)b * 2112 + 2048 + l] = f2bf(attn);
}

// ---------------- LayerNorm (in-place on d_out) ----------------
__global__ __launch_bounds__(256) void ln_k(float* __restrict__ y,
                                            const float* __restrict__ lw,
                                            const float* __restrict__ lb) {
  const int b = blockIdx.x, t = threadIdx.x;
  float* row = y + (size_t)b * 2048;
  float4 v0 = *(const float4*)(row + t * 8);
  float4 v1 = *(const float4*)(row + t * 8 + 4);
  float s = v0.x + v0.y + v0.z + v0.w + v1.x + v1.y + v1.z + v1.w;
  float s2 = v0.x * v0.x + v0.y * v0.y + v0.z * v0.z + v0.w * v0.w +
             v1.x * v1.x + v1.y * v1.y + v1.z * v1.z + v1.w * v1.w;
  #pragma unroll
  for (int d = 1; d < 64; d <<= 1) { s += __shfl_xor(s, d); s2 += __shfl_xor(s2, d); }
  __shared__ float red[8];
  if ((t & 63) == 0) { red[t >> 6] = s; red[4 + (t >> 6)] = s2; }
  __syncthreads();
  float ts = red[0] + red[1] + red[2] + red[3];
  float ts2 = red[4] + red[5] + red[6] + red[7];
  const float mu = ts * (1.f / 2048.f);
  const float inv = 1.f / sqrtf(ts2 * (1.f / 2048.f) - mu * mu + 1e-5f);
  float4 w0 = *(const float4*)(lw + t * 8), w1 = *(const float4*)(lw + t * 8 + 4);
  float4 b0 = *(const float4*)(lb + t * 8), b1 = *(const float4*)(lb + t * 8 + 4);
  float4 o0, o1;
  o0.x = (v0.x - mu) * inv * w0.x + b0.x;
  o0.y = (v0.y - mu) * inv * w0.y + b0.y;
  o0.z = (v0.z - mu) * inv * w0.z + b0.z;
  o0.w = (v0.w - mu) * inv * w0.w + b0.w;
  o1.x = (v1.x - mu) * inv * w1.x + b1.x;
  o1.y = (v1.y - mu) * inv * w1.y + b1.y;
  o1.z = (v1.z - mu) * inv * w1.z + b1.z;
  o1.w = (v1.w - mu) * inv * w1.w + b1.w;
  *(float4*)(row + t * 8) = o0;
  *(float4*)(row + t * 8 + 4) = o1;
}

// ---------------- launch ----------------
extern "C" void kernel_launch(void* const* d_in, const int* in_sizes, int n_in,
                              void* d_out, int out_size, void* d_ws, size_t ws_size,
                              hipStream_t stream) {
  const float* x      = (const float*)d_in[0];
  const float* protos = (const float*)d_in[1];
  const float* conf   = (const float*)d_in[2];
  const float* age    = (const float*)d_in[3];
  const float* ev     = (const float*)d_in[4];
  const float* W_in   = (const float*)d_in[5];
  const float* b_in   = (const float*)d_in[6];
  const float* Wr1    = (const float*)d_in[7];
  const float* br1    = (const float*)d_in[8];
  const float* Wr2    = (const float*)d_in[9];
  const float* br2    = (const float*)d_in[10];
  const float* W_out  = (const float*)d_in[11];
  const float* b_out  = (const float*)d_in[12];
  const float* ln_w   = (const float*)d_in[13];
  const float* ln_b   = (const float*)d_in[14];
  float* out = (float*)d_out;

  char* ws = (char*)d_ws;
  size_t off = 0;
  auto take = [&](size_t bytes) {
    char* p = ws + off;
    off = (off + bytes + 255) & ~(size_t)255;
    return p;
  };
  ushort_t* xa    = (ushort_t*)take((size_t)16384 * 2112 * 2);
  uint8_t*  xa8   = (uint8_t*)take((size_t)16384 * 2048);
  uint8_t*  wbig8 = (uint8_t*)take((size_t)3200 * 2048);
  ushort_t* wwm   = (ushort_t*)take((size_t)2048 * 2112 * 2);
  ushort_t* rbf   = (ushort_t*)take((size_t)16384 * 1024 * 2);
  float*    rproj = (float*)take((size_t)16384 * 64 * 4);
  float*    rn2   = (float*)take((size_t)16384 * 4);
  float*    pnorm = (float*)take((size_t)64 * 2048 * 4);
  float*    base  = (float*)take(256);
  float*    cs    = (float*)take(256);
  float*    dvec  = (float*)take(256);
  (void)in_sizes; (void)n_in; (void)out_size; (void)ws_size;

  hipMemsetAsync(rn2, 0, 16384 * 4, stream);
  prep_scal<<<1, 64, 0, stream>>>(conf, age, ev, base, cs);
  prep_pnorm<<<64, 256, 0, stream>>>(protos, b_in, pnorm, dvec);
  conv_x<<<16384, 256, 0, stream>>>(x, xa, xa8);
  conv_wbig8<<<3200, 256, 0, stream>>>(W_in, Wr1, wbig8);
  conv_ww<<<2048, 256, 0, stream>>>(W_out, wwm);
  small_p2<<<dim3(16, 8), 256, 0, stream>>>(pnorm, W_in, wbig8);
  small_R<<<128, 256, 0, stream>>>(protos, W_out, wwm);
  // HEAD GEMM (fp8): M=16384, N=3200 (rows 3136-3199 zero), K=2048
  gemm_head_fp8<<<dim3(128, 25), 256, 0, stream>>>(xa8, wbig8,
                                                   b_in, br1, rn2, rbf, rproj);
  attn_k<<<4096, 256, 0, stream>>>(rbf, Wr2, br2, rn2, rproj, dvec, base, cs, xa);
  // OUT GEMM (bf16): M=16384, N=2048, K=2112
  gemm_out<<<dim3(128, 16), 256, 0, stream>>>(xa, wwm, b_out, x, out);
  ln_k<<<16384, 256, 0, stream>>>(out, ln_w, ln_b);
}

// Round 12
// 848.095 us; speedup vs baseline: 1.2034x; 1.1440x over previous
//
#include <hip/hip_runtime.h>
#include <hip/hip_bf16.h>
#include <cstdint>

#define DEV __device__ __forceinline__

typedef __bf16 bf16x8 __attribute__((ext_vector_type(8)));
typedef float f32x4 __attribute__((ext_vector_type(4)));
typedef unsigned short ushort_t;
typedef ushort_t ushort8 __attribute__((ext_vector_type(8)));

DEV ushort_t f2bf(float f) {
  union { float f; uint32_t u; } x; x.f = f;
  uint32_t r = (x.u + 0x7fffu + ((x.u >> 16) & 1u)) >> 16;
  return (ushort_t)r;
}
DEV float bf2f(ushort_t b) {
  union { uint32_t u; float f; } x; x.u = ((uint32_t)b) << 16;
  return x.f;
}
DEV float gelu_exact(float v) {
  return 0.5f * v * (1.0f + erff(v * 0.70710678118654752f));
}
DEV void gload_lds16(const void* g, void* l) {
  __builtin_amdgcn_global_load_lds(
      (const __attribute__((address_space(1))) void*)g,
      (__attribute__((address_space(3))) void*)l, 16, 0, 0);
}

// ---------------- prep kernels ----------------

__global__ __launch_bounds__(64) void prep_scal(
    const float* __restrict__ conf, const float* __restrict__ age,
    const float* __restrict__ ev, float* __restrict__ base, float* __restrict__ cs) {
  int l = threadIdx.x;  // 64
  float e = ev[l];
  float m = e;
  #pragma unroll
  for (int d = 1; d < 64; d <<= 1) m = fmaxf(m, __shfl_xor(m, d));
  float freq = logf(e + 1.f) / (logf(m + 2.f) + 1e-8f);
  base[l] = 0.2f * expf(-age[l] * (1.f / 200.f)) + 0.15f * freq + 0.1f * conf[l] + 0.09f;
  cs[l] = 0.45f * conf[l];
}

__global__ __launch_bounds__(256) void prep_pnorm(
    const float* __restrict__ protos, const float* __restrict__ b_in,
    float* __restrict__ p_norm, float* __restrict__ dvec) {
  const int s = blockIdx.x, t = threadIdx.x;
  const float* p = protos + (size_t)s * 2048;
  float vals[8];
  float ss = 0.f, sb = 0.f;
  #pragma unroll
  for (int ii = 0; ii < 2; ++ii) {
    float4 v = *(const float4*)(p + t * 8 + ii * 4);
    float4 bi = *(const float4*)(b_in + t * 8 + ii * 4);
    vals[ii * 4 + 0] = v.x; vals[ii * 4 + 1] = v.y; vals[ii * 4 + 2] = v.z; vals[ii * 4 + 3] = v.w;
    ss += v.x * v.x + v.y * v.y + v.z * v.z + v.w * v.w;
    sb += v.x * bi.x + v.y * bi.y + v.z * bi.z + v.w * bi.w;
  }
  #pragma unroll
  for (int d = 1; d < 64; d <<= 1) { ss += __shfl_xor(ss, d); sb += __shfl_xor(sb, d); }
  __shared__ float red[8];
  if ((t & 63) == 0) { red[t >> 6] = ss; red[4 + (t >> 6)] = sb; }
  __syncthreads();
  ss = red[0] + red[1] + red[2] + red[3];
  sb = red[4] + red[5] + red[6] + red[7];
  float inv = 1.f / fmaxf(sqrtf(ss), 1e-12f);
  #pragma unroll
  for (int k = 0; k < 8; ++k) p_norm[(size_t)s * 2048 + t * 8 + k] = vals[k] * inv;
  if (t == 0) dvec[s] = sb * inv;
}

// ---------------- conversion kernels ----------------

__global__ __launch_bounds__(256) void conv_x(const float* __restrict__ x, ushort_t* __restrict__ xa) {
  size_t e = ((size_t)blockIdx.x * 256 + threadIdx.x) * 8;
  int row = (int)(e >> 11), col = (int)(e & 2047);
  float4 f0 = *(const float4*)(x + e);
  float4 f1 = *(const float4*)(x + e + 4);
  ushort8 o;
  o[0] = f2bf(f0.x); o[1] = f2bf(f0.y); o[2] = f2bf(f0.z); o[3] = f2bf(f0.w);
  o[4] = f2bf(f1.x); o[5] = f2bf(f1.y); o[6] = f2bf(f1.z); o[7] = f2bf(f1.w);
  *(ushort8*)(xa + (size_t)row * 2112 + col) = o;
}

__global__ __launch_bounds__(256) void conv_wbig(const float* __restrict__ W_in,
                                                 const float* __restrict__ Wr1,
                                                 ushort_t* __restrict__ wbig) {
  size_t e = ((size_t)blockIdx.x * 256 + threadIdx.x) * 8;
  int row = (int)(e >> 11), col = (int)(e & 2047);
  if (row >= 3072 && row < 3136) return;  // P2 region, filled by small_p2
  ushort8 o;
  if (row < 3072) {
    const float* src = (row < 2048) ? (W_in + (size_t)row * 2048 + col)
                                    : (Wr1 + (size_t)(row - 2048) * 2048 + col);
    float4 f0 = *(const float4*)(src);
    float4 f1 = *(const float4*)(src + 4);
    o[0] = f2bf(f0.x); o[1] = f2bf(f0.y); o[2] = f2bf(f0.z); o[3] = f2bf(f0.w);
    o[4] = f2bf(f1.x); o[5] = f2bf(f1.y); o[6] = f2bf(f1.z); o[7] = f2bf(f1.w);
  } else {
    o = ushort8{0, 0, 0, 0, 0, 0, 0, 0};
  }
  *(ushort8*)(wbig + (size_t)row * 2048 + col) = o;
}

__global__ __launch_bounds__(256) void conv_ww(const float* __restrict__ W_out,
                                               ushort_t* __restrict__ wwm) {
  size_t e = ((size_t)blockIdx.x * 256 + threadIdx.x) * 8;
  int n = (int)(e >> 11), c = (int)(e & 2047);
  float4 f0 = *(const float4*)(W_out + (size_t)n * 4096 + c);
  float4 f1 = *(const float4*)(W_out + (size_t)n * 4096 + c + 4);
  ushort8 o;
  o[0] = f2bf(f0.x); o[1] = f2bf(f0.y); o[2] = f2bf(f0.z); o[3] = f2bf(f0.w);
  o[4] = f2bf(f1.x); o[5] = f2bf(f1.y); o[6] = f2bf(f1.z); o[7] = f2bf(f1.w);
  *(ushort8*)(wwm + (size_t)n * 2112 + c) = o;
}

// P2[s][k] = sum_j p_norm[s][j] * W_in[j][k]  -> bf16 into wbig rows 3072+s
__global__ __launch_bounds__(256) void small_p2(const float* __restrict__ p_norm,
                                                const float* __restrict__ W_in,
                                                ushort_t* __restrict__ wbig) {
  __shared__ float pn[8][128];
  const int t = threadIdx.x;
  const int k = blockIdx.x * 128 + (t & 127);
  const int sh = t >> 7;  // 0/1
  const int s0 = blockIdx.y * 8;
  float acc[4] = {0.f, 0.f, 0.f, 0.f};
  for (int j0 = 0; j0 < 2048; j0 += 128) {
    __syncthreads();
    {
      int sl = t >> 5;           // 0..7
      int j4 = (t & 31) * 4;     // 0..124
      *(float4*)&pn[sl][j4] = *(const float4*)&p_norm[(size_t)(s0 + sl) * 2048 + j0 + j4];
    }
    __syncthreads();
    #pragma unroll 8
    for (int jj = 0; jj < 128; ++jj) {
      float wv = W_in[(size_t)(j0 + jj) * 2048 + k];
      #pragma unroll
      for (int i = 0; i < 4; ++i) acc[i] += pn[sh * 4 + i][jj] * wv;
    }
  }
  #pragma unroll
  for (int i = 0; i < 4; ++i)
    wbig[(size_t)(3072 + s0 + sh * 4 + i) * 2048 + k] = f2bf(acc[i]);
}

// Rt[n][s] = sum_k protos[s][k] * W_out[n][2048+k] -> bf16 into wwm cols 2048+s
__global__ __launch_bounds__(256) void small_R(const float* __restrict__ protos,
                                               const float* __restrict__ W_out,
                                               ushort_t* __restrict__ wwm) {
  __shared__ float pch[64][68];
  __shared__ float wch[16][68];
  const int t = threadIdx.x;
  const int n_loc = t >> 4;  // 0..15
  const int sb = t & 15;
  const int n0 = blockIdx.x * 16;
  float acc[4] = {0.f, 0.f, 0.f, 0.f};
  for (int k0 = 0; k0 < 2048; k0 += 64) {
    __syncthreads();
    #pragma unroll
    for (int ii = 0; ii < 4; ++ii) {
      int lin4 = t * 4 + ii;      // 0..1023
      int s = lin4 >> 4;          // 0..63
      int k4 = (lin4 & 15) * 4;
      *(float4*)&pch[s][k4] = *(const float4*)&protos[(size_t)s * 2048 + k0 + k4];
    }
    {
      int n_l = t >> 4;
      int k4 = (t & 15) * 4;
      *(float4*)&wch[n_l][k4] = *(const float4*)&W_out[(size_t)(n0 + n_l) * 4096 + 2048 + k0 + k4];
    }
    __syncthreads();
    #pragma unroll 8
    for (int kk = 0; kk < 64; ++kk) {
      float wv = wch[n_loc][kk];
      #pragma unroll
      for (int i = 0; i < 4; ++i) acc[i] += pch[sb + 16 * i][kk] * wv;
    }
  }
  #pragma unroll
  for (int i = 0; i < 4; ++i)
    wwm[(size_t)(n0 + n_loc) * 2112 + 2048 + sb + 16 * i] = f2bf(acc[i]);
}

// ---------------- HEAD GEMM (bf16, m97 structure, BK=32 -- best measured) ----------------
// A=xa (K=2048 slice of lda=2112), B=wbig (3200x2048). cols<2048 -> rownorm2 partials
// (race-free per-bn-tile store, NO atomics); 2048..3071 -> gelu(+br1) -> r_bf;
// 3072..3135 -> raw_proj; >=3136 skip (zero rows).
__global__ __launch_bounds__(256) void gemm_head(
    const ushort_t* __restrict__ A, const ushort_t* __restrict__ Bw,
    const float* __restrict__ bias0, const float* __restrict__ bias1,
    float* __restrict__ rn2part, ushort_t* __restrict__ out1, float* __restrict__ out2) {
  __shared__ ushort_t As[128 * 32];
  __shared__ ushort_t Bs[128 * 32];
  const int tid = threadIdx.x;
  const int w = tid >> 6, l = tid & 63;
  const int bm = blockIdx.x * 128;
  const int bn = blockIdx.y * 128;
  const int srow = tid >> 2;
  const int scol = (tid & 3) * 8;
  const int wm = (w >> 1) * 64, wn = (w & 1) * 64;
  const int lr = l & 15, lk = (l >> 4) * 8;

  f32x4 acc[4][4];
  #pragma unroll
  for (int i = 0; i < 4; ++i)
    #pragma unroll
    for (int j = 0; j < 4; ++j) acc[i][j] = f32x4{0.f, 0.f, 0.f, 0.f};

  for (int k0 = 0; k0 < 2048; k0 += 32) {
    __syncthreads();
    #pragma unroll
    for (int r = 0; r < 2; ++r) {
      int row = srow + r * 64;
      gload_lds16(A + (size_t)(bm + row) * 2112 + k0 + scol,
                  (char*)As + (size_t)(r * 256 + tid) * 16);
    }
    #pragma unroll
    for (int r = 0; r < 2; ++r) {
      int row = srow + r * 64;
      gload_lds16(Bw + (size_t)(bn + row) * 2048 + k0 + scol,
                  (char*)Bs + (size_t)(r * 256 + tid) * 16);
    }
    __syncthreads();
    bf16x8 af[4], bf_[4];
    #pragma unroll
    for (int i = 0; i < 4; ++i) af[i] = *(const bf16x8*)&As[(wm + i * 16 + lr) * 32 + lk];
    #pragma unroll
    for (int j = 0; j < 4; ++j) bf_[j] = *(const bf16x8*)&Bs[(wn + j * 16 + lr) * 32 + lk];
    #pragma unroll
    for (int i = 0; i < 4; ++i)
      #pragma unroll
      for (int j = 0; j < 4; ++j)
        acc[i][j] = __builtin_amdgcn_mfma_f32_16x16x32_bf16(af[i], bf_[j], acc[i][j], 0, 0, 0);
  }

  const int lg = l >> 4;
  #pragma unroll
  for (int i = 0; i < 4; ++i) {
    #pragma unroll
    for (int q = 0; q < 4; ++q) {
      const int grow = bm + wm + i * 16 + lg * 4 + q;
      float ss = 0.f;
      #pragma unroll
      for (int j = 0; j < 4; ++j) {
        const int gcol = bn + wn + j * 16 + lr;
        float v = acc[i][j][q];
        if (gcol < 2048) {
          v += bias0[gcol];
          ss += v * v;
        } else if (gcol < 3072) {
          v += bias1[gcol - 2048];
          out1[(size_t)grow * 1024 + (gcol - 2048)] = f2bf(gelu_exact(v));
        } else if (gcol < 3136) {
          out2[(size_t)grow * 64 + (gcol - 3072)] = v;
        }
      }
      if (bn < 2048) {
        ss += __shfl_xor(ss, 1);
        ss += __shfl_xor(ss, 2);
        ss += __shfl_xor(ss, 4);
        ss += __shfl_xor(ss, 8);
        // race-free: unique (grow, bn-tile) per store; 16 bn-tiles cover cols<2048
        if (lr == 0) rn2part[(size_t)grow * 16 + blockIdx.y] = ss;
      }
    }
  }
}

// ---------------- OUT GEMM (bf16, m97 structure; residual read as bf16 from xa) --------
// A=xa (K=2112), B=wwm (2048x2112). out = gelu(acc+b_out) + bf16(x) -> d_out (f32).
__global__ __launch_bounds__(256) void gemm_out(
    const ushort_t* __restrict__ A, const ushort_t* __restrict__ Bw,
    const float* __restrict__ bias0, float* __restrict__ out0) {
  __shared__ ushort_t As[128 * 32];
  __shared__ ushort_t Bs[128 * 32];
  const int tid = threadIdx.x;
  const int w = tid >> 6, l = tid & 63;
  const int bm = blockIdx.x * 128;
  const int bn = blockIdx.y * 128;
  const int srow = tid >> 2;
  const int scol = (tid & 3) * 8;
  const int wm = (w >> 1) * 64, wn = (w & 1) * 64;
  const int lr = l & 15, lk = (l >> 4) * 8;

  f32x4 acc[4][4];
  #pragma unroll
  for (int i = 0; i < 4; ++i)
    #pragma unroll
    for (int j = 0; j < 4; ++j) acc[i][j] = f32x4{0.f, 0.f, 0.f, 0.f};

  for (int k0 = 0; k0 < 2112; k0 += 32) {
    __syncthreads();
    #pragma unroll
    for (int r = 0; r < 2; ++r) {
      int row = srow + r * 64;
      gload_lds16(A + (size_t)(bm + row) * 2112 + k0 + scol,
                  (char*)As + (size_t)(r * 256 + tid) * 16);
    }
    #pragma unroll
    for (int r = 0; r < 2; ++r) {
      int row = srow + r * 64;
      gload_lds16(Bw + (size_t)(bn + row) * 2112 + k0 + scol,
                  (char*)Bs + (size_t)(r * 256 + tid) * 16);
    }
    __syncthreads();
    bf16x8 af[4], bf_[4];
    #pragma unroll
    for (int i = 0; i < 4; ++i) af[i] = *(const bf16x8*)&As[(wm + i * 16 + lr) * 32 + lk];
    #pragma unroll
    for (int j = 0; j < 4; ++j) bf_[j] = *(const bf16x8*)&Bs[(wn + j * 16 + lr) * 32 + lk];
    #pragma unroll
    for (int i = 0; i < 4; ++i)
      #pragma unroll
      for (int j = 0; j < 4; ++j)
        acc[i][j] = __builtin_amdgcn_mfma_f32_16x16x32_bf16(af[i], bf_[j], acc[i][j], 0, 0, 0);
  }

  const int lg = l >> 4;
  #pragma unroll
  for (int i = 0; i < 4; ++i)
    #pragma unroll
    for (int j = 0; j < 4; ++j)
      #pragma unroll
      for (int q = 0; q < 4; ++q) {
        const int grow = bm + wm + i * 16 + lg * 4 + q;
        const int gcol = bn + wn + j * 16 + lr;
        float v = acc[i][j][q] + bias0[gcol];
        float g = gelu_exact(v);
        out0[(size_t)grow * 2048 + gcol] = g + bf2f(A[(size_t)grow * 2112 + gcol]);
      }
}

// ---------------- attention / salience kernel (1 wave per row) ----------------
__global__ __launch_bounds__(256) void attn_k(
    const ushort_t* __restrict__ r_bf, const float* __restrict__ Wr2,
    const float* __restrict__ br2, const float* __restrict__ rn2p,
    const float* __restrict__ rproj, const float* __restrict__ dvec,
    const float* __restrict__ base, const float* __restrict__ cs,
    ushort_t* __restrict__ xa) {
  const int b = blockIdx.x * 4 + (threadIdx.x >> 6);
  const int l = threadIdx.x & 63;
  const ushort_t* rrow = r_bf + (size_t)b * 1024;
  float t0 = 0.f, t1 = 0.f, t2 = 0.f, t3 = 0.f;
  #pragma unroll
  for (int m = 0; m < 16; ++m) {
    int k = l + m * 64;
    float rv = bf2f(rrow[k]);
    t0 += rv * Wr2[k];
    t1 += rv * Wr2[1024 + k];
    t2 += rv * Wr2[2048 + k];
    t3 += rv * Wr2[3072 + k];
  }
  #pragma unroll
  for (int d = 1; d < 64; d <<= 1) {
    t0 += __shfl_xor(t0, d); t1 += __shfl_xor(t1, d);
    t2 += __shfl_xor(t2, d); t3 += __shfl_xor(t3, d);
  }
  t0 += br2[0]; t1 += br2[1]; t2 += br2[2]; t3 += br2[3];
  float mx = fmaxf(fmaxf(t0, t1), fmaxf(t2, t3));
  float e0 = expf(t0 - mx), e1 = expf(t1 - mx), e2 = expf(t2 - mx), e3 = expf(t3 - mx);
  float sinv = 1.f / (e0 + e1 + e2 + e3);
  float tw0 = e0 * sinv, tw1 = e1 * sinv, tw2 = e2 * sinv, tw3 = e3 * sinv;
  const int ty = l >> 4;
  float twv = (ty == 0) ? tw0 : ((ty == 1) ? tw1 : ((ty == 2) ? tw2 : tw3));

  // rownorm^2 = sum of the 16 per-bn-tile partials (race-free, written by gemm_head)
  float rsum = 0.f;
  #pragma unroll
  for (int t = 0; t < 16; ++t) rsum += rn2p[(size_t)b * 16 + t];
  float inv = 1.f / fmaxf(sqrtf(rsum), 1e-12f);
  float rp = rproj[(size_t)b * 64 + l] + dvec[l];
  float sal = cs[l] * twv * (rp * inv) + base[l];
  sal = fminf(fmaxf(sal, 0.f), 1.f);
  float logit = sal * (1.f / 0.07f);
  float lm = logit;
  #pragma unroll
  for (int d = 1; d < 64; d <<= 1) lm = fmaxf(lm, __shfl_xor(lm, d));
  float ex = expf(logit - lm);
  float es = ex;
  #pragma unroll
  for (int d = 1; d < 64; d <<= 1) es += __shfl_xor(es, d);
  float attn = ex / es;
  xa[(size_t)b * 2112 + 2048 + l] = f2bf(attn);
}

// ---------------- LayerNorm (in-place on d_out) ----------------
__global__ __launch_bounds__(256) void ln_k(float* __restrict__ y,
                                            const float* __restrict__ lw,
                                            const float* __restrict__ lb) {
  const int b = blockIdx.x, t = threadIdx.x;
  float* row = y + (size_t)b * 2048;
  float4 v0 = *(const float4*)(row + t * 8);
  float4 v1 = *(const float4*)(row + t * 8 + 4);
  float s = v0.x + v0.y + v0.z + v0.w + v1.x + v1.y + v1.z + v1.w;
  float s2 = v0.x * v0.x + v0.y * v0.y + v0.z * v0.z + v0.w * v0.w +
             v1.x * v1.x + v1.y * v1.y + v1.z * v1.z + v1.w * v1.w;
  #pragma unroll
  for (int d = 1; d < 64; d <<= 1) { s += __shfl_xor(s, d); s2 += __shfl_xor(s2, d); }
  __shared__ float red[8];
  if ((t & 63) == 0) { red[t >> 6] = s; red[4 + (t >> 6)] = s2; }
  __syncthreads();
  float ts = red[0] + red[1] + red[2] + red[3];
  float ts2 = red[4] + red[5] + red[6] + red[7];
  const float mu = ts * (1.f / 2048.f);
  const float inv = 1.f / sqrtf(ts2 * (1.f / 2048.f) - mu * mu + 1e-5f);
  float4 w0 = *(const float4*)(lw + t * 8), w1 = *(const float4*)(lw + t * 8 + 4);
  float4 b0 = *(const float4*)(lb + t * 8), b1 = *(const float4*)(lb + t * 8 + 4);
  float4 o0, o1;
  o0.x = (v0.x - mu) * inv * w0.x + b0.x;
  o0.y = (v0.y - mu) * inv * w0.y + b0.y;
  o0.z = (v0.z - mu) * inv * w0.z + b0.z;
  o0.w = (v0.w - mu) * inv * w0.w + b0.w;
  o1.x = (v1.x - mu) * inv * w1.x + b1.x;
  o1.y = (v1.y - mu) * inv * w1.y + b1.y;
  o1.z = (v1.z - mu) * inv * w1.z + b1.z;
  o1.w = (v1.w - mu) * inv * w1.w + b1.w;
  *(float4*)(row + t * 8) = o0;
  *(float4*)(row + t * 8 + 4) = o1;
}

// ---------------- launch ----------------
extern "C" void kernel_launch(void* const* d_in, const int* in_sizes, int n_in,
                              void* d_out, int out_size, void* d_ws, size_t ws_size,
                              hipStream_t stream) {
  const float* x      = (const float*)d_in[0];
  const float* protos = (const float*)d_in[1];
  const float* conf   = (const float*)d_in[2];
  const float* age    = (const float*)d_in[3];
  const float* ev     = (const float*)d_in[4];
  const float* W_in   = (const float*)d_in[5];
  const float* b_in   = (const float*)d_in[6];
  const float* Wr1    = (const float*)d_in[7];
  const float* br1    = (const float*)d_in[8];
  const float* Wr2    = (const float*)d_in[9];
  const float* br2    = (const float*)d_in[10];
  const float* W_out  = (const float*)d_in[11];
  const float* b_out  = (const float*)d_in[12];
  const float* ln_w   = (const float*)d_in[13];
  const float* ln_b   = (const float*)d_in[14];
  float* out = (float*)d_out;

  char* ws = (char*)d_ws;
  size_t off = 0;
  auto take = [&](size_t bytes) {
    char* p = ws + off;
    off = (off + bytes + 255) & ~(size_t)255;
    return p;
  };
  ushort_t* xa     = (ushort_t*)take((size_t)16384 * 2112 * 2);
  ushort_t* wbig   = (ushort_t*)take((size_t)3200 * 2048 * 2);
  ushort_t* wwm    = (ushort_t*)take((size_t)2048 * 2112 * 2);
  ushort_t* rbf    = (ushort_t*)take((size_t)16384 * 1024 * 2);
  float*    rproj  = (float*)take((size_t)16384 * 64 * 4);
  float*    rn2p   = (float*)take((size_t)16384 * 16 * 4);
  float*    pnorm  = (float*)take((size_t)64 * 2048 * 4);
  float*    base   = (float*)take(256);
  float*    cs     = (float*)take(256);
  float*    dvec   = (float*)take(256);
  (void)in_sizes; (void)n_in; (void)out_size; (void)ws_size;

  prep_scal<<<1, 64, 0, stream>>>(conf, age, ev, base, cs);
  prep_pnorm<<<64, 256, 0, stream>>>(protos, b_in, pnorm, dvec);
  conv_x<<<16384, 256, 0, stream>>>(x, xa);
  conv_wbig<<<3200, 256, 0, stream>>>(W_in, Wr1, wbig);
  conv_ww<<<2048, 256, 0, stream>>>(W_out, wwm);
  small_p2<<<dim3(16, 8), 256, 0, stream>>>(pnorm, W_in, wbig);
  small_R<<<128, 256, 0, stream>>>(protos, W_out, wwm);
  // HEAD GEMM: M=16384, N=3200 (rows 3136-3199 zero), K=2048
  gemm_head<<<dim3(128, 25), 256, 0, stream>>>(xa, wbig, b_in, br1, rn2p, rbf, rproj);
  attn_k<<<4096, 256, 0, stream>>>(rbf, Wr2, br2, rn2p, rproj, dvec, base, cs, xa);
  // OUT GEMM: M=16384, N=2048, K=2112
  gemm_out<<<dim3(128, 16), 256, 0, stream>>>(xa, wwm, b_out, out);
  ln_k<<<16384, 256, 0, stream>>>(out, ln_w, ln_b);
}